// Round 16
// baseline (372.020 us; speedup 1.0000x reference)
//
#include <hip/hip_runtime.h>
#include <hip/hip_bf16.h>

#define NN 100000
#define EE 1600000
#define OFFP (NN + 8)                             // padded off array
#define BS 1024                                   // bucket node size
#define NBUK ((NN + BS - 1) / BS)                 // 98 buckets
#define P_CH 128                                  // partition chunks per type
#define PCHUNK_E (EE / P_CH)                      // 12500
#define AP 104                                    // bf16 LDS row pad (208 B)

typedef __attribute__((ext_vector_type(8))) short bf16x8;
typedef __attribute__((ext_vector_type(4))) float f32x4;

__device__ inline unsigned short f2bf(float f) {
    unsigned u = __float_as_uint(f);
    return (unsigned short)((u + 0x7FFFu + ((u >> 16) & 1u)) >> 16);
}
__device__ inline float bf2f(unsigned short u) {
    return __uint_as_float(((unsigned)u) << 16);
}
// self-consistent e4m3-style fp8 (encode+decode agree; flush <2^-7; sat ~448)
__device__ inline unsigned char f2fp8(float f) {
    float a = fabsf(f);
    if (a < 0.0078125f) return (f < 0.f) ? 0x80 : 0;
    if (a > 448.f) a = 448.f;
    unsigned u = __float_as_uint(a);
    u += 0x0007FFFFu + ((u >> 20) & 1u);
    int e = ((u >> 23) & 0xFF) - 127;
    unsigned m = (u >> 20) & 7u;
    unsigned char b = (unsigned char)(((e + 7) << 3) | m);
    if (f < 0.f) b |= 0x80;
    return b;
}
__device__ inline float fp82f(unsigned char b) {
    unsigned e = (b >> 3) & 0xFu;
    unsigned m = b & 7u;
    unsigned u = ((unsigned)(b & 0x80u) << 24) | ((e + 120u) << 23) | (m << 20);
    return (b & 0x7F) ? __uint_as_float(u) : 0.f;
}

// ---- trans: emh_bf = bf16(relu(cat(h,e)@W)); ef_f8 = fp8(e_feat) ----
__global__ __launch_bounds__(256) void trans_k(const float* __restrict__ h_feat,
                                               const float* __restrict__ e_feat,
                                               const float* __restrict__ W_trans,
                                               unsigned short* __restrict__ emh_bf,
                                               unsigned char* __restrict__ ef_f8) {
    __shared__ float Wl[48 * 32];
    for (int i = threadIdx.x; i < 48 * 32; i += 256) Wl[i] = W_trans[i];
    __syncthreads();
    int t = blockIdx.x * 256 + threadIdx.x;
    if (t >= NN * 32) return;
    int n = t >> 5, j = t & 31;
    const float* hrow = h_feat + (size_t)n * 32;
    const float* erow = e_feat + (size_t)n * 16;
    float acc = 0.f;
#pragma unroll 8
    for (int k = 0; k < 32; ++k) acc = fmaf(hrow[k], Wl[k * 32 + j], acc);
#pragma unroll 8
    for (int k = 0; k < 16; ++k) acc = fmaf(erow[k], Wl[(32 + k) * 32 + j], acc);
    emh_bf[t] = f2bf(fmaxf(acc, 0.f));
    if (j < 16) ef_f8[(size_t)n * 16 + j] = f2fp8(erow[j]);
}

// ---- count2: per-(chunk, bucket) counts. 256 blocks x 256 thr ----
__global__ __launch_bounds__(256) void count2_k(const int* __restrict__ dst_a,
                                                const int* __restrict__ dst_b,
                                                int* __restrict__ count2) {
    __shared__ int bins[NBUK];
    for (int i = threadIdx.x; i < NBUK; i += 256) bins[i] = 0;
    __syncthreads();
    const int t = blockIdx.x >> 7;
    const int c = blockIdx.x & 127;
    const int* dst = t ? dst_b : dst_a;
    const long base = (long)c * PCHUNK_E;
    for (int i = threadIdx.x * 4; i < PCHUNK_E; i += 1024) {
        int4 d = *reinterpret_cast<const int4*>(dst + base + i);
        atomicAdd(&bins[d.x >> 10], 1);
        atomicAdd(&bins[d.y >> 10], 1);
        atomicAdd(&bins[d.z >> 10], 1);
        atomicAdd(&bins[d.w >> 10], 1);
    }
    __syncthreads();
    int* out = count2 + ((long)t * P_CH + c) * NBUK;
    for (int i = threadIdx.x; i < NBUK; i += 256) out[i] = bins[i];
}

// ---- cur2x: bucket bases + per-(chunk,bucket) exclusive cursors. 1 block ----
__global__ __launch_bounds__(1024) void cur2x_k(const int* __restrict__ count2,
                                                int* __restrict__ cur2,
                                                int* __restrict__ bbase_g) {
    __shared__ int tot[2 * NBUK];
    __shared__ int bb[2 * NBUK];
    const int tid = threadIdx.x;
    for (int i = tid; i < 2 * NBUK; i += 1024) tot[i] = 0;
    __syncthreads();
    for (int idx = tid; idx < 2 * P_CH * NBUK; idx += 1024) {
        int tb = idx / (P_CH * NBUK);
        int b = idx % NBUK;
        atomicAdd(&tot[tb * NBUK + b], count2[idx]);
    }
    __syncthreads();
    if (tid < 2) {
        int r = 0;
        for (int b = 0; b < NBUK; ++b) { int x = tot[tid * NBUK + b]; bb[tid * NBUK + b] = r; r += x; }
    }
    __syncthreads();
    for (int i = tid; i < 2 * NBUK; i += 1024) bbase_g[i] = bb[i];
    const int lane = tid & 63, wid = tid >> 6;
    for (int u = wid; u < 2 * NBUK; u += 16) {
        int t = u / NBUK, b = u % NBUK;
        int base = bb[u];
        int c0 = lane * 2;
        long i0 = ((long)t * P_CH + c0) * NBUK + b;
        long i1 = ((long)t * P_CH + c0 + 1) * NBUK + b;
        int v0 = count2[i0], v1 = count2[i1];
        int ps = v0 + v1, inc = ps;
#pragma unroll
        for (int d = 1; d < 64; d <<= 1) {
            int x = __shfl_up(inc, d);
            if (lane >= d) inc += x;
        }
        int excl = inc - ps;
        cur2[i0] = base + excl;
        cur2[i1] = base + excl + v0;
    }
}

// ---- part: bucket partition. 256 blocks x 1024 thr, no global atomics ----
__global__ __launch_bounds__(1024) void part_k(const int* __restrict__ dst_a,
                                               const int* __restrict__ src_a,
                                               const float* __restrict__ w_a,
                                               const int* __restrict__ dst_b,
                                               const int* __restrict__ src_b,
                                               const float* __restrict__ w_b,
                                               const int* __restrict__ cur2,
                                               int2* __restrict__ inter_a,
                                               int2* __restrict__ inter_b) {
    __shared__ int lcur[NBUK];
    const int t = blockIdx.x >> 7;
    const int c = blockIdx.x & 127;
    const int* dst = t ? dst_b : dst_a;
    const int* src = t ? src_b : src_a;
    const float* wv = t ? w_b : w_a;
    int2* inter = t ? inter_b : inter_a;
    {
        const int* cin = cur2 + ((long)t * P_CH + c) * NBUK;
        for (int i = threadIdx.x; i < NBUK; i += 1024) lcur[i] = cin[i];
    }
    __syncthreads();
    const long base = (long)c * PCHUNK_E;
    for (int i = threadIdx.x * 4; i < PCHUNK_E; i += 4096) {
        int4 d = *reinterpret_cast<const int4*>(dst + base + i);
        int4 s = *reinterpret_cast<const int4*>(src + base + i);
        float4 w = *reinterpret_cast<const float4*>(wv + base + i);
        int pos;
        pos = atomicAdd(&lcur[d.x >> 10], 1);
        inter[pos] = make_int2(s.x | ((d.x & 1023) << 20), __float_as_int(w.x));
        pos = atomicAdd(&lcur[d.y >> 10], 1);
        inter[pos] = make_int2(s.y | ((d.y & 1023) << 20), __float_as_int(w.y));
        pos = atomicAdd(&lcur[d.z >> 10], 1);
        inter[pos] = make_int2(s.z | ((d.z & 1023) << 20), __float_as_int(w.z));
        pos = atomicAdd(&lcur[d.w >> 10], 1);
        inter[pos] = make_int2(s.w | ((d.w & 1023) << 20), __float_as_int(w.w));
    }
}

// ---- scat2: in-LDS node hist+scan -> off[] ; then within-bucket scatter ----
// 196 blocks x 1024 thr. Block (t,b) owns csr window [bb, bhi) (L2-resident).
__global__ __launch_bounds__(1024) void scat2_k(const int2* __restrict__ inter_a,
                                                const int2* __restrict__ inter_b,
                                                const int* __restrict__ bbase_g,
                                                int* __restrict__ off_a,
                                                int* __restrict__ off_b,
                                                int2* __restrict__ csr_a,
                                                int2* __restrict__ csr_b) {
    __shared__ int cnt[BS];
    __shared__ int wsum[16];
    const int tid = threadIdx.x;
    const int t = ((int)blockIdx.x >= NBUK) ? 1 : 0;
    const int b = (int)blockIdx.x - t * NBUK;
    const int2* inter = t ? inter_b : inter_a;
    int* off = t ? off_b : off_a;
    int2* csr = t ? csr_b : csr_a;
    const int n0 = b * BS;
    const int nn = ((n0 + BS < NN) ? BS : NN - n0);
    const int blo = bbase_g[t * NBUK + b];
    const int bhi = (b < NBUK - 1) ? bbase_g[t * NBUK + b + 1] : EE;
    cnt[tid] = 0;
    __syncthreads();
    for (int i = blo + tid; i < bhi; i += 1024) {
        int dloc = (inter[i].x >> 20) & 1023;
        atomicAdd(&cnt[dloc], 1);
    }
    __syncthreads();
    int v = cnt[tid];
    int lane = tid & 63, wid = tid >> 6;
    int inc = v;
#pragma unroll
    for (int d = 1; d < 64; d <<= 1) {
        int x = __shfl_up(inc, d);
        if (lane >= d) inc += x;
    }
    if (lane == 63) wsum[wid] = inc;
    __syncthreads();
    if (tid == 0) {
        int r = 0;
#pragma unroll
        for (int q = 0; q < 16; ++q) { int x = wsum[q]; wsum[q] = r; r += x; }
    }
    __syncthreads();
    int excl = blo + wsum[wid] + inc - v;
    if (tid < nn) off[n0 + tid] = excl;
    if (b == NBUK - 1 && tid == 0) off[NN] = EE;
    cnt[tid] = excl;
    __syncthreads();
    for (int i = blo + tid; i < bhi; i += 1024) {
        int2 e = inter[i];
        int dloc = (e.x >> 20) & 1023;
        int pos = atomicAdd(&cnt[dloc], 1);
        csr[pos] = make_int2(e.x & 0xFFFFF, e.y);
    }
}

// ---- pull1: h (bf16 emh gather), gx/gy (fp8 ef gather). 32 lanes/node ----
__global__ __launch_bounds__(256) void pull1_k(const unsigned short* __restrict__ emh_bf,
                                               const unsigned char* __restrict__ ef_f8,
                                               const float* __restrict__ e_feat,
                                               const int2* __restrict__ csr_a,
                                               const int* __restrict__ off_a,
                                               const int2* __restrict__ csr_b,
                                               const int* __restrict__ off_b,
                                               float* __restrict__ out_h,
                                               float* __restrict__ gx,
                                               float* __restrict__ gy,
                                               unsigned char* __restrict__ gx_f8,
                                               unsigned char* __restrict__ gy_f8) {
    int g = blockIdx.x * 256 + threadIdx.x;
    int n = g >> 5, j = g & 31;
    if (n >= NN) return;
    float acc_h = 0.f;

#pragma unroll
    for (int half = 0; half < 2; ++half) {
        const int2* csr = half ? csr_b : csr_a;
        const int* off = half ? off_b : off_a;
        float* gout = half ? gy : gx;
        unsigned char* gf8 = half ? gy_f8 : gx_f8;
        float acc_g = 0.f, sumw = 0.f;
        int k = off[n], e2 = off[n + 1];
        for (; k + 3 < e2; k += 4) {
            int2 s0 = csr[k], s1 = csr[k + 1], s2 = csr[k + 2], s3 = csr[k + 3];
            float m0 = bf2f(emh_bf[(size_t)s0.x * 32 + j]);
            float m1 = bf2f(emh_bf[(size_t)s1.x * 32 + j]);
            float m2 = bf2f(emh_bf[(size_t)s2.x * 32 + j]);
            float m3 = bf2f(emh_bf[(size_t)s3.x * 32 + j]);
            acc_h += (m0 + m1) + (m2 + m3);
            if (j < 16) {
                float w0 = __int_as_float(s0.y), w1 = __int_as_float(s1.y);
                float w2 = __int_as_float(s2.y), w3 = __int_as_float(s3.y);
                acc_g = fmaf(w0, fp82f(ef_f8[(size_t)s0.x * 16 + j]), acc_g);
                acc_g = fmaf(w1, fp82f(ef_f8[(size_t)s1.x * 16 + j]), acc_g);
                acc_g = fmaf(w2, fp82f(ef_f8[(size_t)s2.x * 16 + j]), acc_g);
                acc_g = fmaf(w3, fp82f(ef_f8[(size_t)s3.x * 16 + j]), acc_g);
                sumw += (w0 + w1) + (w2 + w3);
            }
        }
        for (; k < e2; ++k) {
            int2 s0 = csr[k];
            acc_h += bf2f(emh_bf[(size_t)s0.x * 32 + j]);
            if (j < 16) {
                float w0 = __int_as_float(s0.y);
                acc_g = fmaf(w0, fp82f(ef_f8[(size_t)s0.x * 16 + j]), acc_g);
                sumw += w0;
            }
        }
        if (j < 16) {
            float val = acc_g - sumw * e_feat[(size_t)n * 16 + j];
            gout[(size_t)n * 16 + j] = val;
            gf8[(size_t)n * 16 + j] = f2fp8(val);
        }
    }
    out_h[(size_t)n * 32 + j] = fmaxf(acc_h, 0.f);
}

// ---- pull2: g2x/g2y from fp8 gx/gy gathers (L2-fit). 16 lanes/node ----
__global__ __launch_bounds__(256) void pull2_k(const float* __restrict__ gx,
                                               const float* __restrict__ gy,
                                               const unsigned char* __restrict__ gx_f8,
                                               const unsigned char* __restrict__ gy_f8,
                                               const int2* __restrict__ csr_a,
                                               const int* __restrict__ off_a,
                                               const int2* __restrict__ csr_b,
                                               const int* __restrict__ off_b,
                                               float* __restrict__ g2x,
                                               float* __restrict__ g2y) {
    int g = blockIdx.x * 256 + threadIdx.x;
    int n = g >> 4, j = g & 15;
    if (n >= NN) return;

#pragma unroll
    for (int half = 0; half < 2; ++half) {
        const int2* csr = half ? csr_b : csr_a;
        const int* off = half ? off_b : off_a;
        const float* gin = half ? gy : gx;
        const unsigned char* gf8 = half ? gy_f8 : gx_f8;
        float* g2 = half ? g2y : g2x;
        float acc = 0.f, sumw = 0.f;
        int k = off[n], e2 = off[n + 1];
        for (; k + 3 < e2; k += 4) {
            int2 s0 = csr[k], s1 = csr[k + 1], s2 = csr[k + 2], s3 = csr[k + 3];
            float w0 = __int_as_float(s0.y), w1 = __int_as_float(s1.y);
            float w2 = __int_as_float(s2.y), w3 = __int_as_float(s3.y);
            acc = fmaf(w0, fp82f(gf8[(size_t)s0.x * 16 + j]), acc);
            acc = fmaf(w1, fp82f(gf8[(size_t)s1.x * 16 + j]), acc);
            acc = fmaf(w2, fp82f(gf8[(size_t)s2.x * 16 + j]), acc);
            acc = fmaf(w3, fp82f(gf8[(size_t)s3.x * 16 + j]), acc);
            sumw += (w0 + w1) + (w2 + w3);
        }
        for (; k < e2; ++k) {
            int2 s0 = csr[k];
            float w0 = __int_as_float(s0.y);
            acc = fmaf(w0, fp82f(gf8[(size_t)s0.x * 16 + j]), acc);
            sumw += w0;
        }
        g2[(size_t)n * 16 + j] = acc - sumw * gin[(size_t)n * 16 + j];
    }
}

// ---------------- final head: bf16 MFMA GEMM (64 nodes/block) ----------------
__global__ __launch_bounds__(256) void final_mfma_k(const float* __restrict__ h,
                                                    const float* __restrict__ gx,
                                                    const float* __restrict__ gy,
                                                    const float* __restrict__ g2x,
                                                    const float* __restrict__ g2y,
                                                    const float* __restrict__ rain0,
                                                    const float* __restrict__ W_rin,
                                                    const float* __restrict__ W_rout,
                                                    float* __restrict__ out_rain) {
    __shared__ __align__(16) unsigned short Wt[128 * AP];  // 26.6 KB
    __shared__ __align__(16) unsigned short At[64 * AP];   // 13.3 KB
    __shared__ float Wo[128];
    const int tid = threadIdx.x;

    for (int i = tid; i < 3072; i += 256) {
        int k = i >> 5;
        int c = (i & 31) * 4;
        float4 wv = *reinterpret_cast<const float4*>(W_rin + k * 128 + c);
        Wt[(c + 0) * AP + k] = f2bf(wv.x);
        Wt[(c + 1) * AP + k] = f2bf(wv.y);
        Wt[(c + 2) * AP + k] = f2bf(wv.z);
        Wt[(c + 3) * AP + k] = f2bf(wv.w);
    }
    if (tid < 128) Wo[tid] = W_rout[tid];

    {
        int n = tid >> 2, q = tid & 3;
        int node = blockIdx.x * 64 + n;
        float f[24];
#define LD4(di, p) { float4 v_ = *reinterpret_cast<const float4*>(p); \
                     f[di] = v_.x; f[di+1] = v_.y; f[di+2] = v_.z; f[di+3] = v_.w; }
        if (node < NN) {
            if (q == 0) {
                LD4(0,  h + (size_t)node * 32 + 0);
                LD4(4,  h + (size_t)node * 32 + 4);
                LD4(8,  h + (size_t)node * 32 + 8);
                LD4(12, h + (size_t)node * 32 + 12);
                LD4(16, h + (size_t)node * 32 + 16);
                LD4(20, h + (size_t)node * 32 + 20);
            } else if (q == 1) {
                LD4(0,  h + (size_t)node * 32 + 24);
                LD4(4,  h + (size_t)node * 32 + 28);
                LD4(8,  gx + (size_t)node * 16 + 0);
                LD4(12, gx + (size_t)node * 16 + 4);
                LD4(16, gx + (size_t)node * 16 + 8);
                LD4(20, gx + (size_t)node * 16 + 12);
            } else if (q == 2) {
                LD4(0,  gy + (size_t)node * 16 + 0);
                LD4(4,  gy + (size_t)node * 16 + 4);
                LD4(8,  gy + (size_t)node * 16 + 8);
                LD4(12, gy + (size_t)node * 16 + 12);
                LD4(16, g2x + (size_t)node * 16 + 0);
                LD4(20, g2x + (size_t)node * 16 + 4);
            } else {
                LD4(0,  g2x + (size_t)node * 16 + 8);
                LD4(4,  g2x + (size_t)node * 16 + 12);
                LD4(8,  g2y + (size_t)node * 16 + 0);
                LD4(12, g2y + (size_t)node * 16 + 4);
                LD4(16, g2y + (size_t)node * 16 + 8);
                LD4(20, g2y + (size_t)node * 16 + 12);
            }
        } else {
#pragma unroll
            for (int i = 0; i < 24; ++i) f[i] = 0.f;
        }
#undef LD4
        unsigned pk[12];
#pragma unroll
        for (int i = 0; i < 12; ++i)
            pk[i] = (unsigned)f2bf(f[2 * i]) | ((unsigned)f2bf(f[2 * i + 1]) << 16);
        char* dp = (char*)At + n * (AP * 2) + q * 48;
        *reinterpret_cast<uint4*>(dp + 0)  = make_uint4(pk[0], pk[1], pk[2], pk[3]);
        *reinterpret_cast<uint4*>(dp + 16) = make_uint4(pk[4], pk[5], pk[6], pk[7]);
        *reinterpret_cast<uint4*>(dp + 32) = make_uint4(pk[8], pk[9], pk[10], pk[11]);
    }
    __syncthreads();

    const int w = tid >> 6;
    const int l = tid & 63;
    const int col = l & 15;
    const int kg = l >> 4;
    const char* Ab = (const char*)At + (w * 16 + col) * (AP * 2) + kg * 16;
    const char* Bb = (const char*)Wt + col * (AP * 2) + kg * 16;

    f32x4 acc[8];
#pragma unroll
    for (int ct = 0; ct < 8; ++ct) acc[ct] = (f32x4){0.f, 0.f, 0.f, 0.f};

#pragma unroll
    for (int ks = 0; ks < 3; ++ks) {
        bf16x8 af = *reinterpret_cast<const bf16x8*>(Ab + ks * 64);
#pragma unroll
        for (int ct = 0; ct < 8; ++ct) {
            bf16x8 bfr = *reinterpret_cast<const bf16x8*>(Bb + ct * 16 * (AP * 2) + ks * 64);
            acc[ct] = __builtin_amdgcn_mfma_f32_16x16x32_bf16(af, bfr, acc[ct], 0, 0, 0);
        }
    }

    float s0 = 0.f, s1 = 0.f, s2 = 0.f, s3 = 0.f;
#pragma unroll
    for (int ct = 0; ct < 8; ++ct) {
        float wo = Wo[ct * 16 + col];
        s0 = fmaf(fmaxf(acc[ct][0], 0.f), wo, s0);
        s1 = fmaf(fmaxf(acc[ct][1], 0.f), wo, s1);
        s2 = fmaf(fmaxf(acc[ct][2], 0.f), wo, s2);
        s3 = fmaf(fmaxf(acc[ct][3], 0.f), wo, s3);
    }
#pragma unroll
    for (int m = 1; m < 16; m <<= 1) {
        s0 += __shfl_xor(s0, m);
        s1 += __shfl_xor(s1, m);
        s2 += __shfl_xor(s2, m);
        s3 += __shfl_xor(s3, m);
    }
    if (col == 0) {
        int row = blockIdx.x * 64 + w * 16 + kg * 4;
        if (row + 0 < NN) out_rain[row + 0] = rain0[row + 0] + s0;
        if (row + 1 < NN) out_rain[row + 1] = rain0[row + 1] + s1;
        if (row + 2 < NN) out_rain[row + 2] = rain0[row + 2] + s2;
        if (row + 3 < NN) out_rain[row + 3] = rain0[row + 3] + s3;
    }
}

extern "C" void kernel_launch(void* const* d_in, const int* in_sizes, int n_in,
                              void* d_out, int out_size, void* d_ws, size_t ws_size,
                              hipStream_t stream) {
    const float* h_feat  = (const float*)d_in[0];
    const float* e_feat  = (const float*)d_in[1];
    const float* rain0   = (const float*)d_in[2];
    const float* w_xx    = (const float*)d_in[3];
    const float* w_yy    = (const float*)d_in[4];
    const float* W_trans = (const float*)d_in[5];
    const float* W_rin   = (const float*)d_in[6];
    const float* W_rout  = (const float*)d_in[7];
    const int* src_xx    = (const int*)d_in[8];
    const int* dst_xx    = (const int*)d_in[9];
    const int* src_yy    = (const int*)d_in[10];
    const int* dst_yy    = (const int*)d_in[11];

    // ws layout:
    unsigned short* emh_bf = (unsigned short*)d_ws;            // 6.4MB
    unsigned char* ef_f8 = (unsigned char*)(emh_bf + (size_t)NN * 32);  // 1.6MB
    unsigned char* gx_f8 = ef_f8 + (size_t)NN * 16;            // 1.6MB
    unsigned char* gy_f8 = gx_f8 + (size_t)NN * 16;            // 1.6MB
    float* gx = (float*)(gy_f8 + (size_t)NN * 16);             // 6.4MB
    float* gy = gx + (size_t)NN * 16;                          // 6.4MB
    int2* csr_xx = (int2*)(gy + (size_t)NN * 16);              // 12.8MB
    int2* csr_yy = csr_xx + EE;                                // 12.8MB
    int* off_xx  = (int*)(csr_yy + EE);                        // OFFP ints
    int* off_yy  = off_xx + OFFP;                              // OFFP ints
    int2* inter_xx = (int2*)(off_yy + OFFP);                   // 12.8MB
    int2* inter_yy = inter_xx + EE;                            // 12.8MB
    float* g2x   = (float*)inter_xx;                           // alias (inter dead after scat2)
    float* g2y   = g2x + (size_t)NN * 16;
    int* count2  = (int*)(inter_yy + EE);                      // 2*128*98 ints
    int* cur2    = count2 + 2 * P_CH * NBUK;                   // same size
    int* bbase_g = cur2 + 2 * P_CH * NBUK;                     // 2*98 ints

    float* out_rain = (float*)d_out;           // NN
    float* out_h    = out_rain + NN;           // NN*32

    trans_k<<<(NN * 32 + 255) / 256, 256, 0, stream>>>(h_feat, e_feat, W_trans,
                                                       emh_bf, ef_f8);

    count2_k<<<2 * P_CH, 256, 0, stream>>>(dst_xx, dst_yy, count2);
    cur2x_k<<<1, 1024, 0, stream>>>(count2, cur2, bbase_g);

    part_k<<<2 * P_CH, 1024, 0, stream>>>(
        dst_xx, src_xx, w_xx, dst_yy, src_yy, w_yy, cur2, inter_xx, inter_yy);

    scat2_k<<<2 * NBUK, 1024, 0, stream>>>(
        inter_xx, inter_yy, bbase_g, off_xx, off_yy, csr_xx, csr_yy);

    pull1_k<<<(NN * 32 + 255) / 256, 256, 0, stream>>>(
        emh_bf, ef_f8, e_feat, csr_xx, off_xx, csr_yy, off_yy,
        out_h, gx, gy, gx_f8, gy_f8);

    pull2_k<<<(NN * 16 + 255) / 256, 256, 0, stream>>>(
        gx, gy, gx_f8, gy_f8, csr_xx, off_xx, csr_yy, off_yy, g2x, g2y);

    final_mfma_k<<<(NN + 63) / 64, 256, 0, stream>>>(
        out_h, gx, gy, g2x, g2y, rain0, W_rin, W_rout, out_rain);
}

// Round 17
// 296.954 us; speedup vs baseline: 1.2528x; 1.2528x over previous
//
#include <hip/hip_runtime.h>
#include <hip/hip_bf16.h>

#define NN 100000
#define EE 1600000
#define OFFP (NN + 8)                             // padded off array
#define BS 1024                                   // bucket node size
#define NBUK ((NN + BS - 1) / BS)                 // 98 buckets
#define P_CH 128                                  // partition chunks per type
#define PCHUNK_E (EE / P_CH)                      // 12500
#define AP 104                                    // bf16 LDS row pad (208 B)

typedef __attribute__((ext_vector_type(8))) short bf16x8;
typedef __attribute__((ext_vector_type(4))) float f32x4;

__device__ inline unsigned short f2bf(float f) {
    unsigned u = __float_as_uint(f);
    return (unsigned short)((u + 0x7FFFu + ((u >> 16) & 1u)) >> 16);
}
__device__ inline float bf2f(unsigned short u) {
    return __uint_as_float(((unsigned)u) << 16);
}

// ---- trans: emh_bf = bf16(relu(cat(h,e)@W)); ef_bf = bf16(e_feat) ----
__global__ __launch_bounds__(256) void trans_k(const float* __restrict__ h_feat,
                                               const float* __restrict__ e_feat,
                                               const float* __restrict__ W_trans,
                                               unsigned short* __restrict__ emh_bf,
                                               unsigned short* __restrict__ ef_bf) {
    __shared__ float Wl[48 * 32];
    for (int i = threadIdx.x; i < 48 * 32; i += 256) Wl[i] = W_trans[i];
    __syncthreads();
    int t = blockIdx.x * 256 + threadIdx.x;
    if (t >= NN * 32) return;
    int n = t >> 5, j = t & 31;
    const float* hrow = h_feat + (size_t)n * 32;
    const float* erow = e_feat + (size_t)n * 16;
    float acc = 0.f;
#pragma unroll 8
    for (int k = 0; k < 32; ++k) acc = fmaf(hrow[k], Wl[k * 32 + j], acc);
#pragma unroll 8
    for (int k = 0; k < 16; ++k) acc = fmaf(erow[k], Wl[(32 + k) * 32 + j], acc);
    emh_bf[t] = f2bf(fmaxf(acc, 0.f));
    if (j < 16) ef_bf[(size_t)n * 16 + j] = f2bf(erow[j]);
}

// ---- count2: per-(chunk, bucket) counts. 256 blocks x 256 thr ----
__global__ __launch_bounds__(256) void count2_k(const int* __restrict__ dst_a,
                                                const int* __restrict__ dst_b,
                                                int* __restrict__ count2) {
    __shared__ int bins[NBUK];
    for (int i = threadIdx.x; i < NBUK; i += 256) bins[i] = 0;
    __syncthreads();
    const int t = blockIdx.x >> 7;
    const int c = blockIdx.x & 127;
    const int* dst = t ? dst_b : dst_a;
    const long base = (long)c * PCHUNK_E;
    for (int i = threadIdx.x * 4; i < PCHUNK_E; i += 1024) {
        int4 d = *reinterpret_cast<const int4*>(dst + base + i);
        atomicAdd(&bins[d.x >> 10], 1);
        atomicAdd(&bins[d.y >> 10], 1);
        atomicAdd(&bins[d.z >> 10], 1);
        atomicAdd(&bins[d.w >> 10], 1);
    }
    __syncthreads();
    int* out = count2 + ((long)t * P_CH + c) * NBUK;
    for (int i = threadIdx.x; i < NBUK; i += 256) out[i] = bins[i];
}

// ---- cur2x: bucket bases + per-(chunk,bucket) exclusive cursors. 1 block ----
__global__ __launch_bounds__(1024) void cur2x_k(const int* __restrict__ count2,
                                                int* __restrict__ cur2,
                                                int* __restrict__ bbase_g) {
    __shared__ int tot[2 * NBUK];
    __shared__ int bb[2 * NBUK];
    const int tid = threadIdx.x;
    for (int i = tid; i < 2 * NBUK; i += 1024) tot[i] = 0;
    __syncthreads();
    for (int idx = tid; idx < 2 * P_CH * NBUK; idx += 1024) {
        int tb = idx / (P_CH * NBUK);
        int b = idx % NBUK;
        atomicAdd(&tot[tb * NBUK + b], count2[idx]);
    }
    __syncthreads();
    if (tid < 2) {
        int r = 0;
        for (int b = 0; b < NBUK; ++b) { int x = tot[tid * NBUK + b]; bb[tid * NBUK + b] = r; r += x; }
    }
    __syncthreads();
    for (int i = tid; i < 2 * NBUK; i += 1024) bbase_g[i] = bb[i];
    const int lane = tid & 63, wid = tid >> 6;
    for (int u = wid; u < 2 * NBUK; u += 16) {
        int t = u / NBUK, b = u % NBUK;
        int base = bb[u];
        int c0 = lane * 2;
        long i0 = ((long)t * P_CH + c0) * NBUK + b;
        long i1 = ((long)t * P_CH + c0 + 1) * NBUK + b;
        int v0 = count2[i0], v1 = count2[i1];
        int ps = v0 + v1, inc = ps;
#pragma unroll
        for (int d = 1; d < 64; d <<= 1) {
            int x = __shfl_up(inc, d);
            if (lane >= d) inc += x;
        }
        int excl = inc - ps;
        cur2[i0] = base + excl;
        cur2[i1] = base + excl + v0;
    }
}

// ---- part: bucket partition. 256 blocks x 1024 thr, no global atomics ----
__global__ __launch_bounds__(1024) void part_k(const int* __restrict__ dst_a,
                                               const int* __restrict__ src_a,
                                               const float* __restrict__ w_a,
                                               const int* __restrict__ dst_b,
                                               const int* __restrict__ src_b,
                                               const float* __restrict__ w_b,
                                               const int* __restrict__ cur2,
                                               int2* __restrict__ inter_a,
                                               int2* __restrict__ inter_b) {
    __shared__ int lcur[NBUK];
    const int t = blockIdx.x >> 7;
    const int c = blockIdx.x & 127;
    const int* dst = t ? dst_b : dst_a;
    const int* src = t ? src_b : src_a;
    const float* wv = t ? w_b : w_a;
    int2* inter = t ? inter_b : inter_a;
    {
        const int* cin = cur2 + ((long)t * P_CH + c) * NBUK;
        for (int i = threadIdx.x; i < NBUK; i += 1024) lcur[i] = cin[i];
    }
    __syncthreads();
    const long base = (long)c * PCHUNK_E;
    for (int i = threadIdx.x * 4; i < PCHUNK_E; i += 4096) {
        int4 d = *reinterpret_cast<const int4*>(dst + base + i);
        int4 s = *reinterpret_cast<const int4*>(src + base + i);
        float4 w = *reinterpret_cast<const float4*>(wv + base + i);
        int pos;
        pos = atomicAdd(&lcur[d.x >> 10], 1);
        inter[pos] = make_int2(s.x | ((d.x & 1023) << 20), __float_as_int(w.x));
        pos = atomicAdd(&lcur[d.y >> 10], 1);
        inter[pos] = make_int2(s.y | ((d.y & 1023) << 20), __float_as_int(w.y));
        pos = atomicAdd(&lcur[d.z >> 10], 1);
        inter[pos] = make_int2(s.z | ((d.z & 1023) << 20), __float_as_int(w.z));
        pos = atomicAdd(&lcur[d.w >> 10], 1);
        inter[pos] = make_int2(s.w | ((d.w & 1023) << 20), __float_as_int(w.w));
    }
}

// ---- scat2: in-LDS node hist+scan -> off[] ; then within-bucket scatter ----
__global__ __launch_bounds__(1024) void scat2_k(const int2* __restrict__ inter_a,
                                                const int2* __restrict__ inter_b,
                                                const int* __restrict__ bbase_g,
                                                int* __restrict__ off_a,
                                                int* __restrict__ off_b,
                                                int2* __restrict__ csr_a,
                                                int2* __restrict__ csr_b) {
    __shared__ int cnt[BS];
    __shared__ int wsum[16];
    const int tid = threadIdx.x;
    const int t = ((int)blockIdx.x >= NBUK) ? 1 : 0;
    const int b = (int)blockIdx.x - t * NBUK;
    const int2* inter = t ? inter_b : inter_a;
    int* off = t ? off_b : off_a;
    int2* csr = t ? csr_b : csr_a;
    const int n0 = b * BS;
    const int nn = ((n0 + BS < NN) ? BS : NN - n0);
    const int blo = bbase_g[t * NBUK + b];
    const int bhi = (b < NBUK - 1) ? bbase_g[t * NBUK + b + 1] : EE;
    cnt[tid] = 0;
    __syncthreads();
    for (int i = blo + tid; i < bhi; i += 1024) {
        int dloc = (inter[i].x >> 20) & 1023;
        atomicAdd(&cnt[dloc], 1);
    }
    __syncthreads();
    int v = cnt[tid];
    int lane = tid & 63, wid = tid >> 6;
    int inc = v;
#pragma unroll
    for (int d = 1; d < 64; d <<= 1) {
        int x = __shfl_up(inc, d);
        if (lane >= d) inc += x;
    }
    if (lane == 63) wsum[wid] = inc;
    __syncthreads();
    if (tid == 0) {
        int r = 0;
#pragma unroll
        for (int q = 0; q < 16; ++q) { int x = wsum[q]; wsum[q] = r; r += x; }
    }
    __syncthreads();
    int excl = blo + wsum[wid] + inc - v;
    if (tid < nn) off[n0 + tid] = excl;
    if (b == NBUK - 1 && tid == 0) off[NN] = EE;
    cnt[tid] = excl;
    __syncthreads();
    for (int i = blo + tid; i < bhi; i += 1024) {
        int2 e = inter[i];
        int dloc = (e.x >> 20) & 1023;
        int pos = atomicAdd(&cnt[dloc], 1);
        csr[pos] = make_int2(e.x & 0xFFFFF, e.y);
    }
}

// ---- pull1: h, gx, gy. bf16 gathers, fp32 accumulate. 32 lanes/node ----
__global__ __launch_bounds__(256) void pull1_k(const unsigned short* __restrict__ emh_bf,
                                               const unsigned short* __restrict__ ef_bf,
                                               const float* __restrict__ e_feat,
                                               const int2* __restrict__ csr_a,
                                               const int* __restrict__ off_a,
                                               const int2* __restrict__ csr_b,
                                               const int* __restrict__ off_b,
                                               float* __restrict__ out_h,
                                               float* __restrict__ gx,
                                               float* __restrict__ gy,
                                               unsigned short* __restrict__ gx_bf,
                                               unsigned short* __restrict__ gy_bf) {
    int g = blockIdx.x * 256 + threadIdx.x;
    int n = g >> 5, j = g & 31;
    if (n >= NN) return;
    float acc_h = 0.f;

#pragma unroll
    for (int half = 0; half < 2; ++half) {
        const int2* csr = half ? csr_b : csr_a;
        const int* off = half ? off_b : off_a;
        float* gout = half ? gy : gx;
        unsigned short* gbf = half ? gy_bf : gx_bf;
        float acc_g = 0.f, sumw = 0.f;
        int k = off[n], e2 = off[n + 1];
        for (; k + 3 < e2; k += 4) {
            int2 s0 = csr[k], s1 = csr[k + 1], s2 = csr[k + 2], s3 = csr[k + 3];
            float m0 = bf2f(emh_bf[(size_t)s0.x * 32 + j]);
            float m1 = bf2f(emh_bf[(size_t)s1.x * 32 + j]);
            float m2 = bf2f(emh_bf[(size_t)s2.x * 32 + j]);
            float m3 = bf2f(emh_bf[(size_t)s3.x * 32 + j]);
            acc_h += (m0 + m1) + (m2 + m3);
            if (j < 16) {
                float w0 = __int_as_float(s0.y), w1 = __int_as_float(s1.y);
                float w2 = __int_as_float(s2.y), w3 = __int_as_float(s3.y);
                acc_g = fmaf(w0, bf2f(ef_bf[(size_t)s0.x * 16 + j]), acc_g);
                acc_g = fmaf(w1, bf2f(ef_bf[(size_t)s1.x * 16 + j]), acc_g);
                acc_g = fmaf(w2, bf2f(ef_bf[(size_t)s2.x * 16 + j]), acc_g);
                acc_g = fmaf(w3, bf2f(ef_bf[(size_t)s3.x * 16 + j]), acc_g);
                sumw += (w0 + w1) + (w2 + w3);
            }
        }
        for (; k < e2; ++k) {
            int2 s0 = csr[k];
            acc_h += bf2f(emh_bf[(size_t)s0.x * 32 + j]);
            if (j < 16) {
                float w0 = __int_as_float(s0.y);
                acc_g = fmaf(w0, bf2f(ef_bf[(size_t)s0.x * 16 + j]), acc_g);
                sumw += w0;
            }
        }
        if (j < 16) {
            float val = acc_g - sumw * e_feat[(size_t)n * 16 + j];
            gout[(size_t)n * 16 + j] = val;
            gbf[(size_t)n * 16 + j] = f2bf(val);
        }
    }
    out_h[(size_t)n * 32 + j] = fmaxf(acc_h, 0.f);
}

// ---- pull2: g2x, g2y. bf16 gathers, fp32 own-node + accumulate. 16 lanes/node ----
__global__ __launch_bounds__(256) void pull2_k(const float* __restrict__ gx,
                                               const float* __restrict__ gy,
                                               const unsigned short* __restrict__ gx_bf,
                                               const unsigned short* __restrict__ gy_bf,
                                               const int2* __restrict__ csr_a,
                                               const int* __restrict__ off_a,
                                               const int2* __restrict__ csr_b,
                                               const int* __restrict__ off_b,
                                               float* __restrict__ g2x,
                                               float* __restrict__ g2y) {
    int g = blockIdx.x * 256 + threadIdx.x;
    int n = g >> 4, j = g & 15;
    if (n >= NN) return;

#pragma unroll
    for (int half = 0; half < 2; ++half) {
        const int2* csr = half ? csr_b : csr_a;
        const int* off = half ? off_b : off_a;
        const float* gin = half ? gy : gx;
        const unsigned short* gbf = half ? gy_bf : gx_bf;
        float* g2 = half ? g2y : g2x;
        float acc = 0.f, sumw = 0.f;
        int k = off[n], e2 = off[n + 1];
        for (; k + 3 < e2; k += 4) {
            int2 s0 = csr[k], s1 = csr[k + 1], s2 = csr[k + 2], s3 = csr[k + 3];
            float w0 = __int_as_float(s0.y), w1 = __int_as_float(s1.y);
            float w2 = __int_as_float(s2.y), w3 = __int_as_float(s3.y);
            acc = fmaf(w0, bf2f(gbf[(size_t)s0.x * 16 + j]), acc);
            acc = fmaf(w1, bf2f(gbf[(size_t)s1.x * 16 + j]), acc);
            acc = fmaf(w2, bf2f(gbf[(size_t)s2.x * 16 + j]), acc);
            acc = fmaf(w3, bf2f(gbf[(size_t)s3.x * 16 + j]), acc);
            sumw += (w0 + w1) + (w2 + w3);
        }
        for (; k < e2; ++k) {
            int2 s0 = csr[k];
            float w0 = __int_as_float(s0.y);
            acc = fmaf(w0, bf2f(gbf[(size_t)s0.x * 16 + j]), acc);
            sumw += w0;
        }
        g2[(size_t)n * 16 + j] = acc - sumw * gin[(size_t)n * 16 + j];
    }
}

// ---------------- final head: bf16 MFMA GEMM (64 nodes/block) ----------------
__global__ __launch_bounds__(256) void final_mfma_k(const float* __restrict__ h,
                                                    const float* __restrict__ gx,
                                                    const float* __restrict__ gy,
                                                    const float* __restrict__ g2x,
                                                    const float* __restrict__ g2y,
                                                    const float* __restrict__ rain0,
                                                    const float* __restrict__ W_rin,
                                                    const float* __restrict__ W_rout,
                                                    float* __restrict__ out_rain) {
    __shared__ __align__(16) unsigned short Wt[128 * AP];  // 26.6 KB
    __shared__ __align__(16) unsigned short At[64 * AP];   // 13.3 KB
    __shared__ float Wo[128];
    const int tid = threadIdx.x;

    for (int i = tid; i < 3072; i += 256) {
        int k = i >> 5;
        int c = (i & 31) * 4;
        float4 wv = *reinterpret_cast<const float4*>(W_rin + k * 128 + c);
        Wt[(c + 0) * AP + k] = f2bf(wv.x);
        Wt[(c + 1) * AP + k] = f2bf(wv.y);
        Wt[(c + 2) * AP + k] = f2bf(wv.z);
        Wt[(c + 3) * AP + k] = f2bf(wv.w);
    }
    if (tid < 128) Wo[tid] = W_rout[tid];

    {
        int n = tid >> 2, q = tid & 3;
        int node = blockIdx.x * 64 + n;
        float f[24];
#define LD4(di, p) { float4 v_ = *reinterpret_cast<const float4*>(p); \
                     f[di] = v_.x; f[di+1] = v_.y; f[di+2] = v_.z; f[di+3] = v_.w; }
        if (node < NN) {
            if (q == 0) {
                LD4(0,  h + (size_t)node * 32 + 0);
                LD4(4,  h + (size_t)node * 32 + 4);
                LD4(8,  h + (size_t)node * 32 + 8);
                LD4(12, h + (size_t)node * 32 + 12);
                LD4(16, h + (size_t)node * 32 + 16);
                LD4(20, h + (size_t)node * 32 + 20);
            } else if (q == 1) {
                LD4(0,  h + (size_t)node * 32 + 24);
                LD4(4,  h + (size_t)node * 32 + 28);
                LD4(8,  gx + (size_t)node * 16 + 0);
                LD4(12, gx + (size_t)node * 16 + 4);
                LD4(16, gx + (size_t)node * 16 + 8);
                LD4(20, gx + (size_t)node * 16 + 12);
            } else if (q == 2) {
                LD4(0,  gy + (size_t)node * 16 + 0);
                LD4(4,  gy + (size_t)node * 16 + 4);
                LD4(8,  gy + (size_t)node * 16 + 8);
                LD4(12, gy + (size_t)node * 16 + 12);
                LD4(16, g2x + (size_t)node * 16 + 0);
                LD4(20, g2x + (size_t)node * 16 + 4);
            } else {
                LD4(0,  g2x + (size_t)node * 16 + 8);
                LD4(4,  g2x + (size_t)node * 16 + 12);
                LD4(8,  g2y + (size_t)node * 16 + 0);
                LD4(12, g2y + (size_t)node * 16 + 4);
                LD4(16, g2y + (size_t)node * 16 + 8);
                LD4(20, g2y + (size_t)node * 16 + 12);
            }
        } else {
#pragma unroll
            for (int i = 0; i < 24; ++i) f[i] = 0.f;
        }
#undef LD4
        unsigned pk[12];
#pragma unroll
        for (int i = 0; i < 12; ++i)
            pk[i] = (unsigned)f2bf(f[2 * i]) | ((unsigned)f2bf(f[2 * i + 1]) << 16);
        char* dp = (char*)At + n * (AP * 2) + q * 48;
        *reinterpret_cast<uint4*>(dp + 0)  = make_uint4(pk[0], pk[1], pk[2], pk[3]);
        *reinterpret_cast<uint4*>(dp + 16) = make_uint4(pk[4], pk[5], pk[6], pk[7]);
        *reinterpret_cast<uint4*>(dp + 32) = make_uint4(pk[8], pk[9], pk[10], pk[11]);
    }
    __syncthreads();

    const int w = tid >> 6;
    const int l = tid & 63;
    const int col = l & 15;
    const int kg = l >> 4;
    const char* Ab = (const char*)At + (w * 16 + col) * (AP * 2) + kg * 16;
    const char* Bb = (const char*)Wt + col * (AP * 2) + kg * 16;

    f32x4 acc[8];
#pragma unroll
    for (int ct = 0; ct < 8; ++ct) acc[ct] = (f32x4){0.f, 0.f, 0.f, 0.f};

#pragma unroll
    for (int ks = 0; ks < 3; ++ks) {
        bf16x8 af = *reinterpret_cast<const bf16x8*>(Ab + ks * 64);
#pragma unroll
        for (int ct = 0; ct < 8; ++ct) {
            bf16x8 bfr = *reinterpret_cast<const bf16x8*>(Bb + ct * 16 * (AP * 2) + ks * 64);
            acc[ct] = __builtin_amdgcn_mfma_f32_16x16x32_bf16(af, bfr, acc[ct], 0, 0, 0);
        }
    }

    float s0 = 0.f, s1 = 0.f, s2 = 0.f, s3 = 0.f;
#pragma unroll
    for (int ct = 0; ct < 8; ++ct) {
        float wo = Wo[ct * 16 + col];
        s0 = fmaf(fmaxf(acc[ct][0], 0.f), wo, s0);
        s1 = fmaf(fmaxf(acc[ct][1], 0.f), wo, s1);
        s2 = fmaf(fmaxf(acc[ct][2], 0.f), wo, s2);
        s3 = fmaf(fmaxf(acc[ct][3], 0.f), wo, s3);
    }
#pragma unroll
    for (int m = 1; m < 16; m <<= 1) {
        s0 += __shfl_xor(s0, m);
        s1 += __shfl_xor(s1, m);
        s2 += __shfl_xor(s2, m);
        s3 += __shfl_xor(s3, m);
    }
    if (col == 0) {
        int row = blockIdx.x * 64 + w * 16 + kg * 4;
        if (row + 0 < NN) out_rain[row + 0] = rain0[row + 0] + s0;
        if (row + 1 < NN) out_rain[row + 1] = rain0[row + 1] + s1;
        if (row + 2 < NN) out_rain[row + 2] = rain0[row + 2] + s2;
        if (row + 3 < NN) out_rain[row + 3] = rain0[row + 3] + s3;
    }
}

extern "C" void kernel_launch(void* const* d_in, const int* in_sizes, int n_in,
                              void* d_out, int out_size, void* d_ws, size_t ws_size,
                              hipStream_t stream) {
    const float* h_feat  = (const float*)d_in[0];
    const float* e_feat  = (const float*)d_in[1];
    const float* rain0   = (const float*)d_in[2];
    const float* w_xx    = (const float*)d_in[3];
    const float* w_yy    = (const float*)d_in[4];
    const float* W_trans = (const float*)d_in[5];
    const float* W_rin   = (const float*)d_in[6];
    const float* W_rout  = (const float*)d_in[7];
    const int* src_xx    = (const int*)d_in[8];
    const int* dst_xx    = (const int*)d_in[9];
    const int* src_yy    = (const int*)d_in[10];
    const int* dst_yy    = (const int*)d_in[11];

    // ws layout:
    unsigned short* emh_bf = (unsigned short*)d_ws;            // 6.4MB
    unsigned short* ef_bf  = emh_bf + (size_t)NN * 32;         // 3.2MB
    unsigned short* gx_bf  = ef_bf + (size_t)NN * 16;          // 3.2MB
    unsigned short* gy_bf  = gx_bf + (size_t)NN * 16;          // 3.2MB
    float* gx = (float*)(gy_bf + (size_t)NN * 16);             // 6.4MB
    float* gy = gx + (size_t)NN * 16;                          // 6.4MB
    int2* csr_xx = (int2*)(gy + (size_t)NN * 16);              // 12.8MB
    int2* csr_yy = csr_xx + EE;                                // 12.8MB
    int* off_xx  = (int*)(csr_yy + EE);                        // OFFP ints
    int* off_yy  = off_xx + OFFP;                              // OFFP ints
    int2* inter_xx = (int2*)(off_yy + OFFP);                   // 12.8MB
    int2* inter_yy = inter_xx + EE;                            // 12.8MB
    float* g2x   = (float*)inter_xx;                           // alias (inter dead after scat2)
    float* g2y   = g2x + (size_t)NN * 16;
    int* count2  = (int*)(inter_yy + EE);                      // 2*128*98 ints
    int* cur2    = count2 + 2 * P_CH * NBUK;                   // same size
    int* bbase_g = cur2 + 2 * P_CH * NBUK;                     // 2*98 ints

    float* out_rain = (float*)d_out;           // NN
    float* out_h    = out_rain + NN;           // NN*32

    trans_k<<<(NN * 32 + 255) / 256, 256, 0, stream>>>(h_feat, e_feat, W_trans,
                                                       emh_bf, ef_bf);

    count2_k<<<2 * P_CH, 256, 0, stream>>>(dst_xx, dst_yy, count2);
    cur2x_k<<<1, 1024, 0, stream>>>(count2, cur2, bbase_g);

    part_k<<<2 * P_CH, 1024, 0, stream>>>(
        dst_xx, src_xx, w_xx, dst_yy, src_yy, w_yy, cur2, inter_xx, inter_yy);

    scat2_k<<<2 * NBUK, 1024, 0, stream>>>(
        inter_xx, inter_yy, bbase_g, off_xx, off_yy, csr_xx, csr_yy);

    pull1_k<<<(NN * 32 + 255) / 256, 256, 0, stream>>>(
        emh_bf, ef_bf, e_feat, csr_xx, off_xx, csr_yy, off_yy,
        out_h, gx, gy, gx_bf, gy_bf);

    pull2_k<<<(NN * 16 + 255) / 256, 256, 0, stream>>>(
        gx, gy, gx_bf, gy_bf, csr_xx, off_xx, csr_yy, off_yy, g2x, g2y);

    final_mfma_k<<<(NN + 63) / 64, 256, 0, stream>>>(
        out_h, gx, gy, g2x, g2y, rain0, W_rin, W_rout, out_rain);
}

// Round 18
// 295.686 us; speedup vs baseline: 1.2582x; 1.0043x over previous
//
#include <hip/hip_runtime.h>
#include <hip/hip_bf16.h>

#define NN 100000
#define EE 1600000
#define OFFP (NN + 8)                             // padded off array
#define BS 1024                                   // bucket node size
#define NBUK ((NN + BS - 1) / BS)                 // 98 buckets
#define P_CH 128                                  // partition chunks per type
#define PCHUNK_E (EE / P_CH)                      // 12500
#define AP 104                                    // bf16 LDS row pad (208 B)

typedef __attribute__((ext_vector_type(8))) short bf16x8;
typedef __attribute__((ext_vector_type(4))) float f32x4;

__device__ inline unsigned short f2bf(float f) {
    unsigned u = __float_as_uint(f);
    return (unsigned short)((u + 0x7FFFu + ((u >> 16) & 1u)) >> 16);
}
__device__ inline float bf2f(unsigned short u) {
    return __uint_as_float(((unsigned)u) << 16);
}

// ---- fused: blocks [0,TB) trans (emh_bf, ef_bf); blocks [TB,TB+256) count2 ----
__global__ __launch_bounds__(256) void fused_tc_k(const float* __restrict__ h_feat,
                                                  const float* __restrict__ e_feat,
                                                  const float* __restrict__ W_trans,
                                                  unsigned short* __restrict__ emh_bf,
                                                  unsigned short* __restrict__ ef_bf,
                                                  const int* __restrict__ dst_a,
                                                  const int* __restrict__ dst_b,
                                                  int* __restrict__ count2, int TB) {
    __shared__ float Wl[48 * 32];
    __shared__ int bins[NBUK];
    if ((int)blockIdx.x < TB) {
        for (int i = threadIdx.x; i < 48 * 32; i += 256) Wl[i] = W_trans[i];
        __syncthreads();
        int t = blockIdx.x * 256 + threadIdx.x;
        if (t >= NN * 32) return;
        int n = t >> 5, j = t & 31;
        const float* hrow = h_feat + (size_t)n * 32;
        const float* erow = e_feat + (size_t)n * 16;
        float acc = 0.f;
#pragma unroll 8
        for (int k = 0; k < 32; ++k) acc = fmaf(hrow[k], Wl[k * 32 + j], acc);
#pragma unroll 8
        for (int k = 0; k < 16; ++k) acc = fmaf(erow[k], Wl[(32 + k) * 32 + j], acc);
        emh_bf[t] = f2bf(fmaxf(acc, 0.f));
        if (j < 16) ef_bf[(size_t)n * 16 + j] = f2bf(erow[j]);
    } else {
        for (int i = threadIdx.x; i < NBUK; i += 256) bins[i] = 0;
        __syncthreads();
        const int idx = (int)blockIdx.x - TB;
        const int t = idx >> 7;
        const int c = idx & 127;
        const int* dst = t ? dst_b : dst_a;
        const long base = (long)c * PCHUNK_E;
        for (int i = threadIdx.x * 4; i < PCHUNK_E; i += 1024) {
            int4 d = *reinterpret_cast<const int4*>(dst + base + i);
            atomicAdd(&bins[d.x >> 10], 1);
            atomicAdd(&bins[d.y >> 10], 1);
            atomicAdd(&bins[d.z >> 10], 1);
            atomicAdd(&bins[d.w >> 10], 1);
        }
        __syncthreads();
        int* out = count2 + ((long)t * P_CH + c) * NBUK;
        for (int i = threadIdx.x; i < NBUK; i += 256) out[i] = bins[i];
    }
}

// ---- cur2x: bucket bases + per-(chunk,bucket) exclusive cursors. 1 block ----
__global__ __launch_bounds__(1024) void cur2x_k(const int* __restrict__ count2,
                                                int* __restrict__ cur2,
                                                int* __restrict__ bbase_g) {
    __shared__ int tot[2 * NBUK];
    __shared__ int bb[2 * NBUK];
    const int tid = threadIdx.x;
    for (int i = tid; i < 2 * NBUK; i += 1024) tot[i] = 0;
    __syncthreads();
    for (int idx = tid; idx < 2 * P_CH * NBUK; idx += 1024) {
        int tb = idx / (P_CH * NBUK);
        int b = idx % NBUK;
        atomicAdd(&tot[tb * NBUK + b], count2[idx]);
    }
    __syncthreads();
    if (tid < 2) {
        int r = 0;
        for (int b = 0; b < NBUK; ++b) { int x = tot[tid * NBUK + b]; bb[tid * NBUK + b] = r; r += x; }
    }
    __syncthreads();
    for (int i = tid; i < 2 * NBUK; i += 1024) bbase_g[i] = bb[i];
    const int lane = tid & 63, wid = tid >> 6;
    for (int u = wid; u < 2 * NBUK; u += 16) {
        int t = u / NBUK, b = u % NBUK;
        int base = bb[u];
        int c0 = lane * 2;
        long i0 = ((long)t * P_CH + c0) * NBUK + b;
        long i1 = ((long)t * P_CH + c0 + 1) * NBUK + b;
        int v0 = count2[i0], v1 = count2[i1];
        int ps = v0 + v1, inc = ps;
#pragma unroll
        for (int d = 1; d < 64; d <<= 1) {
            int x = __shfl_up(inc, d);
            if (lane >= d) inc += x;
        }
        int excl = inc - ps;
        cur2[i0] = base + excl;
        cur2[i1] = base + excl + v0;
    }
}

// ---- part: bucket partition. 256 blocks x 1024 thr, no global atomics ----
__global__ __launch_bounds__(1024) void part_k(const int* __restrict__ dst_a,
                                               const int* __restrict__ src_a,
                                               const float* __restrict__ w_a,
                                               const int* __restrict__ dst_b,
                                               const int* __restrict__ src_b,
                                               const float* __restrict__ w_b,
                                               const int* __restrict__ cur2,
                                               int2* __restrict__ inter_a,
                                               int2* __restrict__ inter_b) {
    __shared__ int lcur[NBUK];
    const int t = blockIdx.x >> 7;
    const int c = blockIdx.x & 127;
    const int* dst = t ? dst_b : dst_a;
    const int* src = t ? src_b : src_a;
    const float* wv = t ? w_b : w_a;
    int2* inter = t ? inter_b : inter_a;
    {
        const int* cin = cur2 + ((long)t * P_CH + c) * NBUK;
        for (int i = threadIdx.x; i < NBUK; i += 1024) lcur[i] = cin[i];
    }
    __syncthreads();
    const long base = (long)c * PCHUNK_E;
    for (int i = threadIdx.x * 4; i < PCHUNK_E; i += 4096) {
        int4 d = *reinterpret_cast<const int4*>(dst + base + i);
        int4 s = *reinterpret_cast<const int4*>(src + base + i);
        float4 w = *reinterpret_cast<const float4*>(wv + base + i);
        int pos;
        pos = atomicAdd(&lcur[d.x >> 10], 1);
        inter[pos] = make_int2(s.x | ((d.x & 1023) << 20), __float_as_int(w.x));
        pos = atomicAdd(&lcur[d.y >> 10], 1);
        inter[pos] = make_int2(s.y | ((d.y & 1023) << 20), __float_as_int(w.y));
        pos = atomicAdd(&lcur[d.z >> 10], 1);
        inter[pos] = make_int2(s.z | ((d.z & 1023) << 20), __float_as_int(w.z));
        pos = atomicAdd(&lcur[d.w >> 10], 1);
        inter[pos] = make_int2(s.w | ((d.w & 1023) << 20), __float_as_int(w.w));
    }
}

// ---- scat2: in-LDS node hist+scan -> off[] ; then within-bucket scatter ----
__global__ __launch_bounds__(1024) void scat2_k(const int2* __restrict__ inter_a,
                                                const int2* __restrict__ inter_b,
                                                const int* __restrict__ bbase_g,
                                                int* __restrict__ off_a,
                                                int* __restrict__ off_b,
                                                int2* __restrict__ csr_a,
                                                int2* __restrict__ csr_b) {
    __shared__ int cnt[BS];
    __shared__ int wsum[16];
    const int tid = threadIdx.x;
    const int t = ((int)blockIdx.x >= NBUK) ? 1 : 0;
    const int b = (int)blockIdx.x - t * NBUK;
    const int2* inter = t ? inter_b : inter_a;
    int* off = t ? off_b : off_a;
    int2* csr = t ? csr_b : csr_a;
    const int n0 = b * BS;
    const int nn = ((n0 + BS < NN) ? BS : NN - n0);
    const int blo = bbase_g[t * NBUK + b];
    const int bhi = (b < NBUK - 1) ? bbase_g[t * NBUK + b + 1] : EE;
    cnt[tid] = 0;
    __syncthreads();
    for (int i = blo + tid; i < bhi; i += 1024) {
        int dloc = (inter[i].x >> 20) & 1023;
        atomicAdd(&cnt[dloc], 1);
    }
    __syncthreads();
    int v = cnt[tid];
    int lane = tid & 63, wid = tid >> 6;
    int inc = v;
#pragma unroll
    for (int d = 1; d < 64; d <<= 1) {
        int x = __shfl_up(inc, d);
        if (lane >= d) inc += x;
    }
    if (lane == 63) wsum[wid] = inc;
    __syncthreads();
    if (tid == 0) {
        int r = 0;
#pragma unroll
        for (int q = 0; q < 16; ++q) { int x = wsum[q]; wsum[q] = r; r += x; }
    }
    __syncthreads();
    int excl = blo + wsum[wid] + inc - v;
    if (tid < nn) off[n0 + tid] = excl;
    if (b == NBUK - 1 && tid == 0) off[NN] = EE;
    cnt[tid] = excl;
    __syncthreads();
    for (int i = blo + tid; i < bhi; i += 1024) {
        int2 e = inter[i];
        int dloc = (e.x >> 20) & 1023;
        int pos = atomicAdd(&cnt[dloc], 1);
        csr[pos] = make_int2(e.x & 0xFFFFF, e.y);
    }
}

// ---- pull1: h, gx, gy. bf16 gathers, fp32 accumulate. 32 lanes/node ----
// gxy_bf[n][32]: gx in [0,16), gy in [16,32) -- one 64B line per node.
__global__ __launch_bounds__(256) void pull1_k(const unsigned short* __restrict__ emh_bf,
                                               const unsigned short* __restrict__ ef_bf,
                                               const float* __restrict__ e_feat,
                                               const int2* __restrict__ csr_a,
                                               const int* __restrict__ off_a,
                                               const int2* __restrict__ csr_b,
                                               const int* __restrict__ off_b,
                                               float* __restrict__ out_h,
                                               float* __restrict__ gx,
                                               float* __restrict__ gy,
                                               unsigned short* __restrict__ gxy_bf) {
    int g = blockIdx.x * 256 + threadIdx.x;
    int n = g >> 5, j = g & 31;
    if (n >= NN) return;
    float acc_h = 0.f;

#pragma unroll
    for (int half = 0; half < 2; ++half) {
        const int2* csr = half ? csr_b : csr_a;
        const int* off = half ? off_b : off_a;
        float* gout = half ? gy : gx;
        float acc_g = 0.f, sumw = 0.f;
        int k = off[n], e2 = off[n + 1];
        for (; k + 3 < e2; k += 4) {
            int2 s0 = csr[k], s1 = csr[k + 1], s2 = csr[k + 2], s3 = csr[k + 3];
            float m0 = bf2f(emh_bf[(size_t)s0.x * 32 + j]);
            float m1 = bf2f(emh_bf[(size_t)s1.x * 32 + j]);
            float m2 = bf2f(emh_bf[(size_t)s2.x * 32 + j]);
            float m3 = bf2f(emh_bf[(size_t)s3.x * 32 + j]);
            acc_h += (m0 + m1) + (m2 + m3);
            if (j < 16) {
                float w0 = __int_as_float(s0.y), w1 = __int_as_float(s1.y);
                float w2 = __int_as_float(s2.y), w3 = __int_as_float(s3.y);
                acc_g = fmaf(w0, bf2f(ef_bf[(size_t)s0.x * 16 + j]), acc_g);
                acc_g = fmaf(w1, bf2f(ef_bf[(size_t)s1.x * 16 + j]), acc_g);
                acc_g = fmaf(w2, bf2f(ef_bf[(size_t)s2.x * 16 + j]), acc_g);
                acc_g = fmaf(w3, bf2f(ef_bf[(size_t)s3.x * 16 + j]), acc_g);
                sumw += (w0 + w1) + (w2 + w3);
            }
        }
        for (; k < e2; ++k) {
            int2 s0 = csr[k];
            acc_h += bf2f(emh_bf[(size_t)s0.x * 32 + j]);
            if (j < 16) {
                float w0 = __int_as_float(s0.y);
                acc_g = fmaf(w0, bf2f(ef_bf[(size_t)s0.x * 16 + j]), acc_g);
                sumw += w0;
            }
        }
        if (j < 16) {
            float val = acc_g - sumw * e_feat[(size_t)n * 16 + j];
            gout[(size_t)n * 16 + j] = val;
            gxy_bf[(size_t)n * 32 + half * 16 + j] = f2bf(val);
        }
    }
    out_h[(size_t)n * 32 + j] = fmaxf(acc_h, 0.f);
}

// ---- pull2: g2x, g2y from merged gxy_bf gathers. 16 lanes/node ----
__global__ __launch_bounds__(256) void pull2_k(const float* __restrict__ gx,
                                               const float* __restrict__ gy,
                                               const unsigned short* __restrict__ gxy_bf,
                                               const int2* __restrict__ csr_a,
                                               const int* __restrict__ off_a,
                                               const int2* __restrict__ csr_b,
                                               const int* __restrict__ off_b,
                                               float* __restrict__ g2x,
                                               float* __restrict__ g2y) {
    int g = blockIdx.x * 256 + threadIdx.x;
    int n = g >> 4, j = g & 15;
    if (n >= NN) return;

#pragma unroll
    for (int half = 0; half < 2; ++half) {
        const int2* csr = half ? csr_b : csr_a;
        const int* off = half ? off_b : off_a;
        const float* gin = half ? gy : gx;
        float* g2 = half ? g2y : g2x;
        const int jo = half * 16 + j;
        float acc = 0.f, sumw = 0.f;
        int k = off[n], e2 = off[n + 1];
        for (; k + 3 < e2; k += 4) {
            int2 s0 = csr[k], s1 = csr[k + 1], s2 = csr[k + 2], s3 = csr[k + 3];
            float w0 = __int_as_float(s0.y), w1 = __int_as_float(s1.y);
            float w2 = __int_as_float(s2.y), w3 = __int_as_float(s3.y);
            acc = fmaf(w0, bf2f(gxy_bf[(size_t)s0.x * 32 + jo]), acc);
            acc = fmaf(w1, bf2f(gxy_bf[(size_t)s1.x * 32 + jo]), acc);
            acc = fmaf(w2, bf2f(gxy_bf[(size_t)s2.x * 32 + jo]), acc);
            acc = fmaf(w3, bf2f(gxy_bf[(size_t)s3.x * 32 + jo]), acc);
            sumw += (w0 + w1) + (w2 + w3);
        }
        for (; k < e2; ++k) {
            int2 s0 = csr[k];
            float w0 = __int_as_float(s0.y);
            acc = fmaf(w0, bf2f(gxy_bf[(size_t)s0.x * 32 + jo]), acc);
            sumw += w0;
        }
        g2[(size_t)n * 16 + j] = acc - sumw * gin[(size_t)n * 16 + j];
    }
}

// ---------------- final head: bf16 MFMA GEMM (64 nodes/block) ----------------
__global__ __launch_bounds__(256) void final_mfma_k(const float* __restrict__ h,
                                                    const float* __restrict__ gx,
                                                    const float* __restrict__ gy,
                                                    const float* __restrict__ g2x,
                                                    const float* __restrict__ g2y,
                                                    const float* __restrict__ rain0,
                                                    const float* __restrict__ W_rin,
                                                    const float* __restrict__ W_rout,
                                                    float* __restrict__ out_rain) {
    __shared__ __align__(16) unsigned short Wt[128 * AP];  // 26.6 KB
    __shared__ __align__(16) unsigned short At[64 * AP];   // 13.3 KB
    __shared__ float Wo[128];
    const int tid = threadIdx.x;

    for (int i = tid; i < 3072; i += 256) {
        int k = i >> 5;
        int c = (i & 31) * 4;
        float4 wv = *reinterpret_cast<const float4*>(W_rin + k * 128 + c);
        Wt[(c + 0) * AP + k] = f2bf(wv.x);
        Wt[(c + 1) * AP + k] = f2bf(wv.y);
        Wt[(c + 2) * AP + k] = f2bf(wv.z);
        Wt[(c + 3) * AP + k] = f2bf(wv.w);
    }
    if (tid < 128) Wo[tid] = W_rout[tid];

    {
        int n = tid >> 2, q = tid & 3;
        int node = blockIdx.x * 64 + n;
        float f[24];
#define LD4(di, p) { float4 v_ = *reinterpret_cast<const float4*>(p); \
                     f[di] = v_.x; f[di+1] = v_.y; f[di+2] = v_.z; f[di+3] = v_.w; }
        if (node < NN) {
            if (q == 0) {
                LD4(0,  h + (size_t)node * 32 + 0);
                LD4(4,  h + (size_t)node * 32 + 4);
                LD4(8,  h + (size_t)node * 32 + 8);
                LD4(12, h + (size_t)node * 32 + 12);
                LD4(16, h + (size_t)node * 32 + 16);
                LD4(20, h + (size_t)node * 32 + 20);
            } else if (q == 1) {
                LD4(0,  h + (size_t)node * 32 + 24);
                LD4(4,  h + (size_t)node * 32 + 28);
                LD4(8,  gx + (size_t)node * 16 + 0);
                LD4(12, gx + (size_t)node * 16 + 4);
                LD4(16, gx + (size_t)node * 16 + 8);
                LD4(20, gx + (size_t)node * 16 + 12);
            } else if (q == 2) {
                LD4(0,  gy + (size_t)node * 16 + 0);
                LD4(4,  gy + (size_t)node * 16 + 4);
                LD4(8,  gy + (size_t)node * 16 + 8);
                LD4(12, gy + (size_t)node * 16 + 12);
                LD4(16, g2x + (size_t)node * 16 + 0);
                LD4(20, g2x + (size_t)node * 16 + 4);
            } else {
                LD4(0,  g2x + (size_t)node * 16 + 8);
                LD4(4,  g2x + (size_t)node * 16 + 12);
                LD4(8,  g2y + (size_t)node * 16 + 0);
                LD4(12, g2y + (size_t)node * 16 + 4);
                LD4(16, g2y + (size_t)node * 16 + 8);
                LD4(20, g2y + (size_t)node * 16 + 12);
            }
        } else {
#pragma unroll
            for (int i = 0; i < 24; ++i) f[i] = 0.f;
        }
#undef LD4
        unsigned pk[12];
#pragma unroll
        for (int i = 0; i < 12; ++i)
            pk[i] = (unsigned)f2bf(f[2 * i]) | ((unsigned)f2bf(f[2 * i + 1]) << 16);
        char* dp = (char*)At + n * (AP * 2) + q * 48;
        *reinterpret_cast<uint4*>(dp + 0)  = make_uint4(pk[0], pk[1], pk[2], pk[3]);
        *reinterpret_cast<uint4*>(dp + 16) = make_uint4(pk[4], pk[5], pk[6], pk[7]);
        *reinterpret_cast<uint4*>(dp + 32) = make_uint4(pk[8], pk[9], pk[10], pk[11]);
    }
    __syncthreads();

    const int w = tid >> 6;
    const int l = tid & 63;
    const int col = l & 15;
    const int kg = l >> 4;
    const char* Ab = (const char*)At + (w * 16 + col) * (AP * 2) + kg * 16;
    const char* Bb = (const char*)Wt + col * (AP * 2) + kg * 16;

    f32x4 acc[8];
#pragma unroll
    for (int ct = 0; ct < 8; ++ct) acc[ct] = (f32x4){0.f, 0.f, 0.f, 0.f};

#pragma unroll
    for (int ks = 0; ks < 3; ++ks) {
        bf16x8 af = *reinterpret_cast<const bf16x8*>(Ab + ks * 64);
#pragma unroll
        for (int ct = 0; ct < 8; ++ct) {
            bf16x8 bfr = *reinterpret_cast<const bf16x8*>(Bb + ct * 16 * (AP * 2) + ks * 64);
            acc[ct] = __builtin_amdgcn_mfma_f32_16x16x32_bf16(af, bfr, acc[ct], 0, 0, 0);
        }
    }

    float s0 = 0.f, s1 = 0.f, s2 = 0.f, s3 = 0.f;
#pragma unroll
    for (int ct = 0; ct < 8; ++ct) {
        float wo = Wo[ct * 16 + col];
        s0 = fmaf(fmaxf(acc[ct][0], 0.f), wo, s0);
        s1 = fmaf(fmaxf(acc[ct][1], 0.f), wo, s1);
        s2 = fmaf(fmaxf(acc[ct][2], 0.f), wo, s2);
        s3 = fmaf(fmaxf(acc[ct][3], 0.f), wo, s3);
    }
#pragma unroll
    for (int m = 1; m < 16; m <<= 1) {
        s0 += __shfl_xor(s0, m);
        s1 += __shfl_xor(s1, m);
        s2 += __shfl_xor(s2, m);
        s3 += __shfl_xor(s3, m);
    }
    if (col == 0) {
        int row = blockIdx.x * 64 + w * 16 + kg * 4;
        if (row + 0 < NN) out_rain[row + 0] = rain0[row + 0] + s0;
        if (row + 1 < NN) out_rain[row + 1] = rain0[row + 1] + s1;
        if (row + 2 < NN) out_rain[row + 2] = rain0[row + 2] + s2;
        if (row + 3 < NN) out_rain[row + 3] = rain0[row + 3] + s3;
    }
}

extern "C" void kernel_launch(void* const* d_in, const int* in_sizes, int n_in,
                              void* d_out, int out_size, void* d_ws, size_t ws_size,
                              hipStream_t stream) {
    const float* h_feat  = (const float*)d_in[0];
    const float* e_feat  = (const float*)d_in[1];
    const float* rain0   = (const float*)d_in[2];
    const float* w_xx    = (const float*)d_in[3];
    const float* w_yy    = (const float*)d_in[4];
    const float* W_trans = (const float*)d_in[5];
    const float* W_rin   = (const float*)d_in[6];
    const float* W_rout  = (const float*)d_in[7];
    const int* src_xx    = (const int*)d_in[8];
    const int* dst_xx    = (const int*)d_in[9];
    const int* src_yy    = (const int*)d_in[10];
    const int* dst_yy    = (const int*)d_in[11];

    // ws layout:
    unsigned short* emh_bf = (unsigned short*)d_ws;            // 6.4MB
    unsigned short* ef_bf  = emh_bf + (size_t)NN * 32;         // 3.2MB
    unsigned short* gxy_bf = ef_bf + (size_t)NN * 16;          // 6.4MB (merged gx|gy)
    float* gx = (float*)(gxy_bf + (size_t)NN * 32);            // 6.4MB
    float* gy = gx + (size_t)NN * 16;                          // 6.4MB
    int2* csr_xx = (int2*)(gy + (size_t)NN * 16);              // 12.8MB
    int2* csr_yy = csr_xx + EE;                                // 12.8MB
    int* off_xx  = (int*)(csr_yy + EE);                        // OFFP ints
    int* off_yy  = off_xx + OFFP;                              // OFFP ints
    int2* inter_xx = (int2*)(off_yy + OFFP);                   // 12.8MB
    int2* inter_yy = inter_xx + EE;                            // 12.8MB
    float* g2x   = (float*)inter_xx;                           // alias (inter dead after scat2)
    float* g2y   = g2x + (size_t)NN * 16;
    int* count2  = (int*)(inter_yy + EE);                      // 2*128*98 ints
    int* cur2    = count2 + 2 * P_CH * NBUK;                   // same size
    int* bbase_g = cur2 + 2 * P_CH * NBUK;                     // 2*98 ints

    float* out_rain = (float*)d_out;           // NN
    float* out_h    = out_rain + NN;           // NN*32

    const int TB = (NN * 32 + 255) / 256;                      // 12500 trans blocks
    fused_tc_k<<<TB + 2 * P_CH, 256, 0, stream>>>(h_feat, e_feat, W_trans,
                                                  emh_bf, ef_bf,
                                                  dst_xx, dst_yy, count2, TB);

    cur2x_k<<<1, 1024, 0, stream>>>(count2, cur2, bbase_g);

    part_k<<<2 * P_CH, 1024, 0, stream>>>(
        dst_xx, src_xx, w_xx, dst_yy, src_yy, w_yy, cur2, inter_xx, inter_yy);

    scat2_k<<<2 * NBUK, 1024, 0, stream>>>(
        inter_xx, inter_yy, bbase_g, off_xx, off_yy, csr_xx, csr_yy);

    pull1_k<<<(NN * 32 + 255) / 256, 256, 0, stream>>>(
        emh_bf, ef_bf, e_feat, csr_xx, off_xx, csr_yy, off_yy,
        out_h, gx, gy, gxy_bf);

    pull2_k<<<(NN * 16 + 255) / 256, 256, 0, stream>>>(
        gx, gy, gxy_bf, csr_xx, off_xx, csr_yy, off_yy, g2x, g2y);

    final_mfma_k<<<(NN + 63) / 64, 256, 0, stream>>>(
        out_h, gx, gy, g2x, g2y, rain0, W_rin, W_rout, out_rain);
}

// Round 19
// 289.794 us; speedup vs baseline: 1.2837x; 1.0203x over previous
//
#include <hip/hip_runtime.h>
#include <hip/hip_bf16.h>

#define NN 100000
#define EE 1600000
#define SCAN_CHUNK 4096
#define NB ((NN + SCAN_CHUNK - 1) / SCAN_CHUNK)   // 25 scan blocks per type
#define OFFP (NN + 8)                             // padded off array
#define NRANGE 4                                  // hist dst ranges
#define RSZ (NN / NRANGE)                         // 25000
#define C_CH 16                                   // hist chunks per type
#define CHUNK_E (EE / C_CH)                       // 100000
#define BS 1024                                   // bucket node size
#define NBUK ((NN + BS - 1) / BS)                 // 98 buckets
#define P_CH 128                                  // phase-1 chunks per type
#define PCHUNK_E (EE / P_CH)                      // 12500
#define AP 104                                    // bf16 LDS row pad (208 B)

typedef __attribute__((ext_vector_type(8))) short bf16x8;
typedef __attribute__((ext_vector_type(4))) float f32x4;

__device__ inline unsigned short f2bf(float f) {
    unsigned u = __float_as_uint(f);
    return (unsigned short)((u + 0x7FFFu + ((u >> 16) & 1u)) >> 16);
}
__device__ inline float bf2f(unsigned short u) {
    return __uint_as_float(((unsigned)u) << 16);
}

// ---- fused: blocks [0,TB) trans (emh_bf, ef_bf); blocks [TB,..) LDS hist ----
__global__ __launch_bounds__(1024) void fused_th_k(const float* __restrict__ h_feat,
                                                   const float* __restrict__ e_feat,
                                                   const float* __restrict__ W_trans,
                                                   unsigned short* __restrict__ emh_bf,
                                                   unsigned short* __restrict__ ef_bf,
                                                   const int* __restrict__ dst_a,
                                                   const int* __restrict__ dst_b,
                                                   int* __restrict__ partial, int TB) {
    __shared__ float Wl[48 * 32];
    __shared__ int bins[RSZ];          // 100 KB
    if ((int)blockIdx.x < TB) {
        for (int i = threadIdx.x; i < 48 * 32; i += 1024) Wl[i] = W_trans[i];
        __syncthreads();
        int t = blockIdx.x * 1024 + threadIdx.x;
        if (t >= NN * 32) return;
        int n = t >> 5, j = t & 31;
        const float* hrow = h_feat + (size_t)n * 32;
        const float* erow = e_feat + (size_t)n * 16;
        float acc = 0.f;
#pragma unroll 8
        for (int k = 0; k < 32; ++k) acc = fmaf(hrow[k], Wl[k * 32 + j], acc);
#pragma unroll 8
        for (int k = 0; k < 16; ++k) acc = fmaf(erow[k], Wl[(32 + k) * 32 + j], acc);
        emh_bf[t] = f2bf(fmaxf(acc, 0.f));
        if (j < 16) ef_bf[(size_t)n * 16 + j] = f2bf(erow[j]);
    } else {
        for (int i = threadIdx.x; i < RSZ; i += 1024) bins[i] = 0;
        __syncthreads();
        const int idx = (int)blockIdx.x - TB;
        const int q = idx & 7;
        const int t = q >> 2;
        const int p = q & 3;
        const int c = idx >> 3;
        const int* dst = t ? dst_b : dst_a;
        const int lo = p * RSZ;
        const long base = (long)c * CHUNK_E;
        for (int i = threadIdx.x * 4; i < CHUNK_E; i += 4096) {
            int4 d = *reinterpret_cast<const int4*>(dst + base + i);
            int x;
            x = d.x - lo; if ((unsigned)x < RSZ) atomicAdd(&bins[x], 1);
            x = d.y - lo; if ((unsigned)x < RSZ) atomicAdd(&bins[x], 1);
            x = d.z - lo; if ((unsigned)x < RSZ) atomicAdd(&bins[x], 1);
            x = d.w - lo; if ((unsigned)x < RSZ) atomicAdd(&bins[x], 1);
        }
        __syncthreads();
        int* pout = partial + (long)(t * C_CH + c) * NN + lo;
        for (int i = threadIdx.x; i < RSZ; i += 1024) pout[i] = bins[i];
    }
}

// ---------------- scan phase A: per-4096-node-chunk totals ----------------
__global__ __launch_bounds__(1024) void scanA_k(const int* __restrict__ partial,
                                                int* __restrict__ bsum) {
    __shared__ int wsum[16];
    const int b = blockIdx.x;
    const int t = (b >= NB) ? 1 : 0;
    const int i0 = (b % NB) * SCAN_CHUNK + threadIdx.x * 4;
    int4 s = make_int4(0, 0, 0, 0);
    if (i0 < NN) {
#pragma unroll
        for (int c = 0; c < C_CH; ++c) {
            int4 v = *reinterpret_cast<const int4*>(partial + (long)(t * C_CH + c) * NN + i0);
            s.x += v.x; s.y += v.y; s.z += v.z; s.w += v.w;
        }
    }
    int tot = s.x + s.y + s.z + s.w;
#pragma unroll
    for (int d = 32; d; d >>= 1) tot += __shfl_down(tot, d);
    int lane = threadIdx.x & 63, w = threadIdx.x >> 6;
    if (lane == 0) wsum[w] = tot;
    __syncthreads();
    if (threadIdx.x == 0) {
        int sm = 0;
#pragma unroll
        for (int q = 0; q < 16; ++q) sm += wsum[q];
        bsum[b] = sm;
    }
}

// ---------------- scan phase B: segmented exclusive scan of block sums ------
__global__ __launch_bounds__(64) void scanB_k(const int* __restrict__ bsum,
                                              int* __restrict__ bbase,
                                              int* __restrict__ off_a,
                                              int* __restrict__ off_b) {
    int lane = threadIdx.x;
    int v = (lane < 2 * NB) ? bsum[lane] : 0;
    int seg = lane / NB;
    int inc = v;
#pragma unroll
    for (int d = 1; d < 64; d <<= 1) {
        int x = __shfl_up(inc, d);
        if (lane >= d && (lane - d) / NB == seg) inc += x;
    }
    int excl = inc - v;
    if (lane < 2 * NB) bbase[lane] = excl;
    if (lane == NB - 1) off_a[NN] = inc;
    if (lane == 2 * NB - 1) off_b[NN] = inc;
}

// ---- scan phase C: off[] = exclusive node scan (no cursor rewrite) ----
__global__ __launch_bounds__(1024) void scanC_k(const int* __restrict__ partial,
                                                int* __restrict__ off_a,
                                                int* __restrict__ off_b,
                                                const int* __restrict__ bbase) {
    __shared__ int wsum[16];
    const int b = blockIdx.x;
    const int t = (b >= NB) ? 1 : 0;
    int* off = t ? off_b : off_a;
    const int base0 = bbase[b];
    const int i0 = (b % NB) * SCAN_CHUNK + threadIdx.x * 4;
    int4 s = make_int4(0, 0, 0, 0);
    if (i0 < NN) {
#pragma unroll
        for (int c = 0; c < C_CH; ++c) {
            int4 v = *reinterpret_cast<const int4*>(partial + (long)(t * C_CH + c) * NN + i0);
            s.x += v.x; s.y += v.y; s.z += v.z; s.w += v.w;
        }
    }
    int s1 = s.x, s2 = s1 + s.y, s3 = s2 + s.z, tot = s3 + s.w;
    int lane = threadIdx.x & 63, w = threadIdx.x >> 6;
    int inc = tot;
#pragma unroll
    for (int d = 1; d < 64; d <<= 1) {
        int x = __shfl_up(inc, d);
        if (lane >= d) inc += x;
    }
    if (lane == 63) wsum[w] = inc;
    int texcl = inc - tot;
    __syncthreads();
    if (threadIdx.x == 0) {
        int r = 0;
#pragma unroll
        for (int q = 0; q < 16; ++q) { int x = wsum[q]; wsum[q] = r; r += x; }
    }
    __syncthreads();
    const int base = base0 + wsum[w] + texcl;
    if (i0 < NN)
        *reinterpret_cast<int4*>(off + i0) = make_int4(base, base + s1, base + s2, base + s3);
}

// ---- count2: per-(phase1-chunk, bucket) counts. 256 blocks x 256 thr ----
__global__ __launch_bounds__(256) void count2_k(const int* __restrict__ dst_a,
                                                const int* __restrict__ dst_b,
                                                int* __restrict__ count2) {
    __shared__ int bins[NBUK];
    for (int i = threadIdx.x; i < NBUK; i += 256) bins[i] = 0;
    __syncthreads();
    const int t = blockIdx.x >> 7;
    const int c = blockIdx.x & 127;
    const int* dst = t ? dst_b : dst_a;
    const long base = (long)c * PCHUNK_E;
    for (int i = threadIdx.x * 4; i < PCHUNK_E; i += 1024) {
        int4 d = *reinterpret_cast<const int4*>(dst + base + i);
        atomicAdd(&bins[d.x >> 10], 1);
        atomicAdd(&bins[d.y >> 10], 1);
        atomicAdd(&bins[d.z >> 10], 1);
        atomicAdd(&bins[d.w >> 10], 1);
    }
    __syncthreads();
    int* out = count2 + ((long)t * P_CH + c) * NBUK;
    for (int i = threadIdx.x; i < NBUK; i += 256) out[i] = bins[i];
}

// ---- cur2: exclusive scan of count2 over chunks; base = off[bucket_start] ----
__global__ __launch_bounds__(256) void cur2_k(const int* __restrict__ count2,
                                              const int* __restrict__ off_a,
                                              const int* __restrict__ off_b,
                                              int* __restrict__ cur2) {
    int tid = threadIdx.x;
    if (tid >= 2 * NBUK) return;
    int t = tid / NBUK;
    int b = tid % NBUK;
    const int* off = t ? off_b : off_a;
    int run = off[b * BS];
    for (int c = 0; c < P_CH; ++c) {
        long idx = ((long)t * P_CH + c) * NBUK + b;
        int v = count2[idx];
        cur2[idx] = run;
        run += v;
    }
}

// ---- part: phase-1 bucket partition. 256 blocks x 1024 thr, no global atomics ----
__global__ __launch_bounds__(1024) void part_k(const int* __restrict__ dst_a,
                                               const int* __restrict__ src_a,
                                               const float* __restrict__ w_a,
                                               const int* __restrict__ dst_b,
                                               const int* __restrict__ src_b,
                                               const float* __restrict__ w_b,
                                               const int* __restrict__ cur2,
                                               int2* __restrict__ inter_a,
                                               int2* __restrict__ inter_b) {
    __shared__ int lcur[NBUK];
    const int t = blockIdx.x >> 7;
    const int c = blockIdx.x & 127;
    const int* dst = t ? dst_b : dst_a;
    const int* src = t ? src_b : src_a;
    const float* wv = t ? w_b : w_a;
    int2* inter = t ? inter_b : inter_a;
    {
        const int* cin = cur2 + ((long)t * P_CH + c) * NBUK;
        for (int i = threadIdx.x; i < NBUK; i += 1024) lcur[i] = cin[i];
    }
    __syncthreads();
    const long base = (long)c * PCHUNK_E;
    for (int i = threadIdx.x * 4; i < PCHUNK_E; i += 4096) {
        int4 d = *reinterpret_cast<const int4*>(dst + base + i);
        int4 s = *reinterpret_cast<const int4*>(src + base + i);
        float4 w = *reinterpret_cast<const float4*>(wv + base + i);
        int pos;
        pos = atomicAdd(&lcur[d.x >> 10], 1);
        inter[pos] = make_int2(s.x | ((d.x & 1023) << 20), __float_as_int(w.x));
        pos = atomicAdd(&lcur[d.y >> 10], 1);
        inter[pos] = make_int2(s.y | ((d.y & 1023) << 20), __float_as_int(w.y));
        pos = atomicAdd(&lcur[d.z >> 10], 1);
        inter[pos] = make_int2(s.z | ((d.z & 1023) << 20), __float_as_int(w.z));
        pos = atomicAdd(&lcur[d.w >> 10], 1);
        inter[pos] = make_int2(s.w | ((d.w & 1023) << 20), __float_as_int(w.w));
    }
}

// ---- scat2: phase-2 within-bucket ordering. 196 blocks x 1024 thr ----
__global__ __launch_bounds__(1024) void scat2_k(const int2* __restrict__ inter_a,
                                                const int2* __restrict__ inter_b,
                                                const int* __restrict__ off_a,
                                                const int* __restrict__ off_b,
                                                int2* __restrict__ csr_a,
                                                int2* __restrict__ csr_b) {
    __shared__ int curs[BS];
    const int t = ((int)blockIdx.x >= NBUK) ? 1 : 0;
    const int b = (int)blockIdx.x - t * NBUK;
    const int2* inter = t ? inter_b : inter_a;
    const int* off = t ? off_b : off_a;
    int2* csr = t ? csr_b : csr_a;
    const int n0 = b * BS;
    const int nend = (n0 + BS < NN) ? n0 + BS : NN;
    for (int i = threadIdx.x; i < nend - n0; i += 1024) curs[i] = off[n0 + i];
    __syncthreads();
    const int lo = off[n0];
    const int hi = off[nend];
    for (int i = lo + threadIdx.x; i < hi; i += 1024) {
        int2 e = inter[i];
        int dloc = (e.x >> 20) & 1023;
        int pos = atomicAdd(&curs[dloc], 1);
        csr[pos] = make_int2(e.x & 0xFFFFF, e.y);
    }
}

// ---- pull1: h, gx, gy. bf16 gathers, fp32 accumulate. 32 lanes/node ----
__global__ __launch_bounds__(256) void pull1_k(const unsigned short* __restrict__ emh_bf,
                                               const unsigned short* __restrict__ ef_bf,
                                               const float* __restrict__ e_feat,
                                               const int2* __restrict__ csr_a,
                                               const int* __restrict__ off_a,
                                               const int2* __restrict__ csr_b,
                                               const int* __restrict__ off_b,
                                               float* __restrict__ out_h,
                                               float* __restrict__ gx,
                                               float* __restrict__ gy,
                                               unsigned short* __restrict__ gx_bf,
                                               unsigned short* __restrict__ gy_bf) {
    int g = blockIdx.x * 256 + threadIdx.x;
    int n = g >> 5, j = g & 31;
    if (n >= NN) return;
    float acc_h = 0.f;

#pragma unroll
    for (int half = 0; half < 2; ++half) {
        const int2* csr = half ? csr_b : csr_a;
        const int* off = half ? off_b : off_a;
        float* gout = half ? gy : gx;
        unsigned short* gbf = half ? gy_bf : gx_bf;
        float acc_g = 0.f, sumw = 0.f;
        int k = off[n], e2 = off[n + 1];
        for (; k + 3 < e2; k += 4) {
            int2 s0 = csr[k], s1 = csr[k + 1], s2 = csr[k + 2], s3 = csr[k + 3];
            float m0 = bf2f(emh_bf[(size_t)s0.x * 32 + j]);
            float m1 = bf2f(emh_bf[(size_t)s1.x * 32 + j]);
            float m2 = bf2f(emh_bf[(size_t)s2.x * 32 + j]);
            float m3 = bf2f(emh_bf[(size_t)s3.x * 32 + j]);
            acc_h += (m0 + m1) + (m2 + m3);
            if (j < 16) {
                float w0 = __int_as_float(s0.y), w1 = __int_as_float(s1.y);
                float w2 = __int_as_float(s2.y), w3 = __int_as_float(s3.y);
                acc_g = fmaf(w0, bf2f(ef_bf[(size_t)s0.x * 16 + j]), acc_g);
                acc_g = fmaf(w1, bf2f(ef_bf[(size_t)s1.x * 16 + j]), acc_g);
                acc_g = fmaf(w2, bf2f(ef_bf[(size_t)s2.x * 16 + j]), acc_g);
                acc_g = fmaf(w3, bf2f(ef_bf[(size_t)s3.x * 16 + j]), acc_g);
                sumw += (w0 + w1) + (w2 + w3);
            }
        }
        for (; k < e2; ++k) {
            int2 s0 = csr[k];
            acc_h += bf2f(emh_bf[(size_t)s0.x * 32 + j]);
            if (j < 16) {
                float w0 = __int_as_float(s0.y);
                acc_g = fmaf(w0, bf2f(ef_bf[(size_t)s0.x * 16 + j]), acc_g);
                sumw += w0;
            }
        }
        if (j < 16) {
            float val = acc_g - sumw * e_feat[(size_t)n * 16 + j];
            gout[(size_t)n * 16 + j] = val;
            gbf[(size_t)n * 16 + j] = f2bf(val);
        }
    }
    out_h[(size_t)n * 32 + j] = fmaxf(acc_h, 0.f);
}

// ---- pull2: g2x, g2y. bf16 gathers, fp32 own-node + accumulate. 16 lanes/node ----
__global__ __launch_bounds__(256) void pull2_k(const float* __restrict__ gx,
                                               const float* __restrict__ gy,
                                               const unsigned short* __restrict__ gx_bf,
                                               const unsigned short* __restrict__ gy_bf,
                                               const int2* __restrict__ csr_a,
                                               const int* __restrict__ off_a,
                                               const int2* __restrict__ csr_b,
                                               const int* __restrict__ off_b,
                                               float* __restrict__ g2x,
                                               float* __restrict__ g2y) {
    int g = blockIdx.x * 256 + threadIdx.x;
    int n = g >> 4, j = g & 15;
    if (n >= NN) return;

#pragma unroll
    for (int half = 0; half < 2; ++half) {
        const int2* csr = half ? csr_b : csr_a;
        const int* off = half ? off_b : off_a;
        const float* gin = half ? gy : gx;
        const unsigned short* gbf = half ? gy_bf : gx_bf;
        float* g2 = half ? g2y : g2x;
        float acc = 0.f, sumw = 0.f;
        int k = off[n], e2 = off[n + 1];
        for (; k + 3 < e2; k += 4) {
            int2 s0 = csr[k], s1 = csr[k + 1], s2 = csr[k + 2], s3 = csr[k + 3];
            float w0 = __int_as_float(s0.y), w1 = __int_as_float(s1.y);
            float w2 = __int_as_float(s2.y), w3 = __int_as_float(s3.y);
            acc = fmaf(w0, bf2f(gbf[(size_t)s0.x * 16 + j]), acc);
            acc = fmaf(w1, bf2f(gbf[(size_t)s1.x * 16 + j]), acc);
            acc = fmaf(w2, bf2f(gbf[(size_t)s2.x * 16 + j]), acc);
            acc = fmaf(w3, bf2f(gbf[(size_t)s3.x * 16 + j]), acc);
            sumw += (w0 + w1) + (w2 + w3);
        }
        for (; k < e2; ++k) {
            int2 s0 = csr[k];
            float w0 = __int_as_float(s0.y);
            acc = fmaf(w0, bf2f(gbf[(size_t)s0.x * 16 + j]), acc);
            sumw += w0;
        }
        g2[(size_t)n * 16 + j] = acc - sumw * gin[(size_t)n * 16 + j];
    }
}

// ---------------- final head: bf16 MFMA GEMM (64 nodes/block) ----------------
__global__ __launch_bounds__(256) void final_mfma_k(const float* __restrict__ h,
                                                    const float* __restrict__ gx,
                                                    const float* __restrict__ gy,
                                                    const float* __restrict__ g2x,
                                                    const float* __restrict__ g2y,
                                                    const float* __restrict__ rain0,
                                                    const float* __restrict__ W_rin,
                                                    const float* __restrict__ W_rout,
                                                    float* __restrict__ out_rain) {
    __shared__ __align__(16) unsigned short Wt[128 * AP];  // 26.6 KB
    __shared__ __align__(16) unsigned short At[64 * AP];   // 13.3 KB
    __shared__ float Wo[128];
    const int tid = threadIdx.x;

    for (int i = tid; i < 3072; i += 256) {
        int k = i >> 5;
        int c = (i & 31) * 4;
        float4 wv = *reinterpret_cast<const float4*>(W_rin + k * 128 + c);
        Wt[(c + 0) * AP + k] = f2bf(wv.x);
        Wt[(c + 1) * AP + k] = f2bf(wv.y);
        Wt[(c + 2) * AP + k] = f2bf(wv.z);
        Wt[(c + 3) * AP + k] = f2bf(wv.w);
    }
    if (tid < 128) Wo[tid] = W_rout[tid];

    {
        int n = tid >> 2, q = tid & 3;
        int node = blockIdx.x * 64 + n;
        float f[24];
#define LD4(di, p) { float4 v_ = *reinterpret_cast<const float4*>(p); \
                     f[di] = v_.x; f[di+1] = v_.y; f[di+2] = v_.z; f[di+3] = v_.w; }
        if (node < NN) {
            if (q == 0) {
                LD4(0,  h + (size_t)node * 32 + 0);
                LD4(4,  h + (size_t)node * 32 + 4);
                LD4(8,  h + (size_t)node * 32 + 8);
                LD4(12, h + (size_t)node * 32 + 12);
                LD4(16, h + (size_t)node * 32 + 16);
                LD4(20, h + (size_t)node * 32 + 20);
            } else if (q == 1) {
                LD4(0,  h + (size_t)node * 32 + 24);
                LD4(4,  h + (size_t)node * 32 + 28);
                LD4(8,  gx + (size_t)node * 16 + 0);
                LD4(12, gx + (size_t)node * 16 + 4);
                LD4(16, gx + (size_t)node * 16 + 8);
                LD4(20, gx + (size_t)node * 16 + 12);
            } else if (q == 2) {
                LD4(0,  gy + (size_t)node * 16 + 0);
                LD4(4,  gy + (size_t)node * 16 + 4);
                LD4(8,  gy + (size_t)node * 16 + 8);
                LD4(12, gy + (size_t)node * 16 + 12);
                LD4(16, g2x + (size_t)node * 16 + 0);
                LD4(20, g2x + (size_t)node * 16 + 4);
            } else {
                LD4(0,  g2x + (size_t)node * 16 + 8);
                LD4(4,  g2x + (size_t)node * 16 + 12);
                LD4(8,  g2y + (size_t)node * 16 + 0);
                LD4(12, g2y + (size_t)node * 16 + 4);
                LD4(16, g2y + (size_t)node * 16 + 8);
                LD4(20, g2y + (size_t)node * 16 + 12);
            }
        } else {
#pragma unroll
            for (int i = 0; i < 24; ++i) f[i] = 0.f;
        }
#undef LD4
        unsigned pk[12];
#pragma unroll
        for (int i = 0; i < 12; ++i)
            pk[i] = (unsigned)f2bf(f[2 * i]) | ((unsigned)f2bf(f[2 * i + 1]) << 16);
        char* dp = (char*)At + n * (AP * 2) + q * 48;
        *reinterpret_cast<uint4*>(dp + 0)  = make_uint4(pk[0], pk[1], pk[2], pk[3]);
        *reinterpret_cast<uint4*>(dp + 16) = make_uint4(pk[4], pk[5], pk[6], pk[7]);
        *reinterpret_cast<uint4*>(dp + 32) = make_uint4(pk[8], pk[9], pk[10], pk[11]);
    }
    __syncthreads();

    const int w = tid >> 6;
    const int l = tid & 63;
    const int col = l & 15;
    const int kg = l >> 4;
    const char* Ab = (const char*)At + (w * 16 + col) * (AP * 2) + kg * 16;
    const char* Bb = (const char*)Wt + col * (AP * 2) + kg * 16;

    f32x4 acc[8];
#pragma unroll
    for (int ct = 0; ct < 8; ++ct) acc[ct] = (f32x4){0.f, 0.f, 0.f, 0.f};

#pragma unroll
    for (int ks = 0; ks < 3; ++ks) {
        bf16x8 af = *reinterpret_cast<const bf16x8*>(Ab + ks * 64);
#pragma unroll
        for (int ct = 0; ct < 8; ++ct) {
            bf16x8 bfr = *reinterpret_cast<const bf16x8*>(Bb + ct * 16 * (AP * 2) + ks * 64);
            acc[ct] = __builtin_amdgcn_mfma_f32_16x16x32_bf16(af, bfr, acc[ct], 0, 0, 0);
        }
    }

    float s0 = 0.f, s1 = 0.f, s2 = 0.f, s3 = 0.f;
#pragma unroll
    for (int ct = 0; ct < 8; ++ct) {
        float wo = Wo[ct * 16 + col];
        s0 = fmaf(fmaxf(acc[ct][0], 0.f), wo, s0);
        s1 = fmaf(fmaxf(acc[ct][1], 0.f), wo, s1);
        s2 = fmaf(fmaxf(acc[ct][2], 0.f), wo, s2);
        s3 = fmaf(fmaxf(acc[ct][3], 0.f), wo, s3);
    }
#pragma unroll
    for (int m = 1; m < 16; m <<= 1) {
        s0 += __shfl_xor(s0, m);
        s1 += __shfl_xor(s1, m);
        s2 += __shfl_xor(s2, m);
        s3 += __shfl_xor(s3, m);
    }
    if (col == 0) {
        int row = blockIdx.x * 64 + w * 16 + kg * 4;
        if (row + 0 < NN) out_rain[row + 0] = rain0[row + 0] + s0;
        if (row + 1 < NN) out_rain[row + 1] = rain0[row + 1] + s1;
        if (row + 2 < NN) out_rain[row + 2] = rain0[row + 2] + s2;
        if (row + 3 < NN) out_rain[row + 3] = rain0[row + 3] + s3;
    }
}

extern "C" void kernel_launch(void* const* d_in, const int* in_sizes, int n_in,
                              void* d_out, int out_size, void* d_ws, size_t ws_size,
                              hipStream_t stream) {
    const float* h_feat  = (const float*)d_in[0];
    const float* e_feat  = (const float*)d_in[1];
    const float* rain0   = (const float*)d_in[2];
    const float* w_xx    = (const float*)d_in[3];
    const float* w_yy    = (const float*)d_in[4];
    const float* W_trans = (const float*)d_in[5];
    const float* W_rin   = (const float*)d_in[6];
    const float* W_rout  = (const float*)d_in[7];
    const int* src_xx    = (const int*)d_in[8];
    const int* dst_xx    = (const int*)d_in[9];
    const int* src_yy    = (const int*)d_in[10];
    const int* dst_yy    = (const int*)d_in[11];

    // ws layout:
    unsigned short* emh_bf = (unsigned short*)d_ws;            // 6.4MB
    unsigned short* ef_bf  = emh_bf + (size_t)NN * 32;         // 3.2MB
    unsigned short* gx_bf  = ef_bf + (size_t)NN * 16;          // 3.2MB
    unsigned short* gy_bf  = gx_bf + (size_t)NN * 16;          // 3.2MB
    float* gx = (float*)(gy_bf + (size_t)NN * 16);             // 6.4MB
    float* gy = gx + (size_t)NN * 16;                          // 6.4MB
    int2* csr_xx = (int2*)(gy + (size_t)NN * 16);              // 12.8MB
    int2* csr_yy = csr_xx + EE;                                // 12.8MB
    int* off_xx  = (int*)(csr_yy + EE);                        // OFFP ints
    int* off_yy  = off_xx + OFFP;                              // OFFP ints
    int* partial = off_yy + OFFP;                              // 12.8MB (dead after scanC)
    int2* inter_xx = (int2*)partial;                           // alias: 12.8MB
    int2* inter_yy = inter_xx + EE;                            // NEW 12.8MB
    float* g2x   = (float*)inter_xx;                           // alias (inter dead after scat2)
    float* g2y   = g2x + (size_t)NN * 16;
    int* tail    = (int*)(inter_yy + EE);
    int* bsum    = tail;                                       // 64
    int* bbase   = bsum + 64;                                  // 64
    int* count2  = bbase + 64;                                 // 2*128*98 ints (~100KB)
    int* cur2    = count2 + 2 * P_CH * NBUK;                   // same size

    float* out_rain = (float*)d_out;           // NN
    float* out_h    = out_rain + NN;           // NN*32

    const int TB = (NN * 32 + 1023) / 1024;                    // 3125 trans blocks
    const int HB = 2 * NRANGE * C_CH;                          // 128 hist blocks
    fused_th_k<<<TB + HB, 1024, 0, stream>>>(h_feat, e_feat, W_trans, emh_bf, ef_bf,
                                             dst_xx, dst_yy, partial, TB);

    scanA_k<<<2 * NB, 1024, 0, stream>>>(partial, bsum);
    scanB_k<<<1, 64, 0, stream>>>(bsum, bbase, off_xx, off_yy);
    scanC_k<<<2 * NB, 1024, 0, stream>>>(partial, off_xx, off_yy, bbase);

    count2_k<<<2 * P_CH, 256, 0, stream>>>(dst_xx, dst_yy, count2);
    cur2_k<<<1, 256, 0, stream>>>(count2, off_xx, off_yy, cur2);

    part_k<<<2 * P_CH, 1024, 0, stream>>>(
        dst_xx, src_xx, w_xx, dst_yy, src_yy, w_yy, cur2, inter_xx, inter_yy);

    scat2_k<<<2 * NBUK, 1024, 0, stream>>>(
        inter_xx, inter_yy, off_xx, off_yy, csr_xx, csr_yy);

    pull1_k<<<(NN * 32 + 255) / 256, 256, 0, stream>>>(
        emh_bf, ef_bf, e_feat, csr_xx, off_xx, csr_yy, off_yy,
        out_h, gx, gy, gx_bf, gy_bf);

    pull2_k<<<(NN * 16 + 255) / 256, 256, 0, stream>>>(
        gx, gy, gx_bf, gy_bf, csr_xx, off_xx, csr_yy, off_yy, g2x, g2y);

    final_mfma_k<<<(NN + 63) / 64, 256, 0, stream>>>(
        out_h, gx, gy, g2x, g2y, rain0, W_rin, W_rout, out_rain);
}